// Round 20
// baseline (143.881 us; speedup 1.0000x reference)
//
#include <hip/hip_runtime.h>

static constexpr int kDim   = 256;
static constexpr int kInner = 64;
static constexpr int kNH    = 8;
static constexpr int kB     = 2;
static constexpr int kP     = 2304;   // 48*48
static constexpr float kScaleL2 = 0.5100697891920077f; // 8^-0.5 * log2(e)
static constexpr float kEps   = 1e-6f;

typedef __fp16   fp16x2 __attribute__((ext_vector_type(2)));
typedef _Float16 half4f __attribute__((ext_vector_type(4)));
typedef _Float16 half8  __attribute__((ext_vector_type(8)));
typedef float    f32x4  __attribute__((ext_vector_type(4)));

// ws layout in halfs:
static constexpr size_t oXq  = 0;          // [4 combo][2304][256]      = 2359296
static constexpr size_t oQ16 = 2359296;    // [2 inp][16 bh][2304][8]   = 589824
static constexpr size_t oK16 = 2949120;    // same                      = 589824
static constexpr size_t oV16 = 3538944;    // [2 inp][16 bh][8][2304]   = 589824
static constexpr size_t oA16 = 4128768;    // [4 combo][2304][64]       = 589824
// Xg aliases [0 .. 4718592): [4 combo][2304][512]  (written after all above dead)
static constexpr size_t oW16 = 7077888;    // weights f16               = 393216
static constexpr size_t kInpStride = 294912; // q16/k16/vt16 per-inp stride (halfs)

// ---------------- prep: blocks <576 do pre-LN (XCD-affine); blocks >=576 cast weights.
__global__ __launch_bounds__(256) void prep(
    const float* __restrict__ x0, const float* __restrict__ w0,
    const float* __restrict__ b0, const float* __restrict__ x1,
    const float* __restrict__ w1, const float* __restrict__ b1,
    _Float16* __restrict__ Xq,
    const float* __restrict__ qr_w, const float* __restrict__ kvr_w,
    const float* __restrict__ qi_w, const float* __restrict__ kvi_w,
    const float* __restrict__ pr_w, const float* __restrict__ pi_w,
    const float* __restrict__ gr_w, const float* __restrict__ gi_w,
    _Float16* __restrict__ w16)
{
    if (blockIdx.x >= 576) {               // weight cast
        const int flat = blockIdx.x - 576;
        const int y = flat >> 6, x = flat & 63;
        const float* src; _Float16* dst; int n;
        _Float16* Aq = w16;             // [2][192][256]
        _Float16* Ap = w16 + 98304;     // [2][256][64]
        _Float16* Ag = w16 + 131072;    // [2][256][512]
        switch (y) {
            case 0: src = qr_w;  dst = Aq;          n = 16384;  break;
            case 1: src = kvr_w; dst = Aq + 16384;  n = 32768;  break;
            case 2: src = qi_w;  dst = Aq + 49152;  n = 16384;  break;
            case 3: src = kvi_w; dst = Aq + 65536;  n = 32768;  break;
            case 4: src = pr_w;  dst = Ap;          n = 16384;  break;
            case 5: src = pi_w;  dst = Ap + 16384;  n = 16384;  break;
            case 6: src = gr_w;  dst = Ag;          n = 131072; break;
            default:src = gi_w;  dst = Ag + 131072; n = 131072; break;
        }
        for (int i = x * 256 + threadIdx.x; i < n; i += 64 * 256)
            dst[i] = (_Float16)src[i];
        return;
    }
    // pre-LN
    __shared__ float sb[16][16];
    __shared__ float ssb[16][16];
    const int fid = blockIdx.x;
    const int xcd = fid & 7, q = fid >> 3;      // q 0..71
    const int inp = (xcd >> 2) & 1, bb = (xcd >> 1) & 1, half = xcd & 1;
    const float* x = inp ? x1 : x0;
    const float* w = inp ? w1 : w0;
    const float* b = inp ? b1 : b0;
    const int pos = threadIdx.x & 15;
    const int grp = threadIdx.x >> 4;
    const int p   = half * 1152 + q * 16 + pos;
    const size_t base = (size_t)bb * kDim * kP + p;
    const int c0 = grp * 16;

    float v[16];
    float s = 0.f, ss = 0.f;
    #pragma unroll
    for (int j = 0; j < 16; ++j) {
        v[j] = x[base + (size_t)(c0 + j) * kP];
        s += v[j]; ss += v[j] * v[j];
    }
    sb[grp][pos] = s; ssb[grp][pos] = ss;
    __syncthreads();
    float st = 0.f, sst = 0.f;
    #pragma unroll
    for (int g = 0; g < 16; ++g) { st += sb[g][pos]; sst += ssb[g][pos]; }
    const float mean = st * (1.f / kDim);
    const float rstd = rsqrtf(sst * (1.f / kDim) - mean * mean + kEps);
    half8 h0, h1;
    #pragma unroll
    for (int j = 0; j < 8; ++j) {
        h0[j] = (_Float16)((v[j]     - mean) * rstd * w[c0 + j]     + b[c0 + j]);
        h1[j] = (_Float16)((v[j + 8] - mean) * rstd * w[c0 + j + 8] + b[c0 + j + 8]);
    }
    _Float16* dst = Xq + ((size_t)(inp * 2 + bb) * kP + p) * 256 + c0;
    *(half8*)dst       = h0;
    *(half8*)(dst + 8) = h1;
}

// ---------------- f16 MFMA GEMM, 64o x 64p block tile, 4 acc-chains per wave.
// XCD-affine flat grid: fid&7 -> (s,bb,half); fid>>3 -> (o-tile64, p-tile64).
// EPI: 0 = qkv routing (Q scaled by kScaleL2 for exp2 softmax), 2 = gate.
template <int M, int K, int EPI>
__global__ __launch_bounds__(256) void gemm_f16(
    const _Float16* __restrict__ A,     // [2][M][K] f16 weights
    const _Float16* __restrict__ B,     // [4][2304][K] f16 activations
    const float* __restrict__ b0, const float* __restrict__ b1,
    const float* __restrict__ b2, const float* __restrict__ b3,
    _Float16* __restrict__ o16a, _Float16* __restrict__ o16b, _Float16* __restrict__ o16c,
    const float* __restrict__ f0, const float* __restrict__ f1,
    float* __restrict__ outp)
{
    constexpr int MT64 = M / 64;
    const int fid = blockIdx.x;
    const int xcd = fid & 7, q = fid >> 3;
    const int s = (xcd >> 2) & 1, bb = (xcd >> 1) & 1, half = xcd & 1;
    const int ot64 = (q % MT64) * 64;
    const int pt   = q / MT64;                 // 0..17
    const int wv = threadIdx.x >> 6, lane = threadIdx.x & 63;
    const int r16 = lane & 15, g = lane >> 4;
    const int ot = ot64 + wv * 16;             // wave's 16-o tile
    const int p0 = half * 1152 + pt * 64;      // block's 64-p tile
    const int combo = s * 2 + bb;

    const _Float16* Ar = A + ((size_t)s * M + ot + r16) * K + 8 * g;
    const _Float16* Br = B + ((size_t)combo * kP + p0 + r16) * K + 8 * g;
    f32x4 acc0[4], acc1[4];
    #pragma unroll
    for (int ps = 0; ps < 4; ++ps) {
        acc0[ps] = (f32x4){0.f, 0.f, 0.f, 0.f};
        acc1[ps] = (f32x4){0.f, 0.f, 0.f, 0.f};
    }
    #pragma unroll 4
    for (int c0 = 0; c0 < K; c0 += 32) {
        const half8 a8 = *(const half8*)(Ar + c0);
        half8 b8[4];
        #pragma unroll
        for (int ps = 0; ps < 4; ++ps)
            b8[ps] = *(const half8*)(Br + (size_t)(16 * ps) * K + c0);
        const half4f al = {a8[0], a8[1], a8[2], a8[3]};
        const half4f ah = {a8[4], a8[5], a8[6], a8[7]};
        #pragma unroll
        for (int ps = 0; ps < 4; ++ps) {
            const half4f bl = {b8[ps][0], b8[ps][1], b8[ps][2], b8[ps][3]};
            const half4f bh = {b8[ps][4], b8[ps][5], b8[ps][6], b8[ps][7]};
            acc0[ps] = __builtin_amdgcn_mfma_f32_16x16x16f16(al, bl, acc0[ps], 0, 0, 0);
            acc1[ps] = __builtin_amdgcn_mfma_f32_16x16x16f16(ah, bh, acc1[ps], 0, 0, 0);
        }
    }
    const int obase = ot + 4 * g;              // o = obase + i

    #pragma unroll
    for (int ps = 0; ps < 4; ++ps) {
        float acc[4];
        #pragma unroll
        for (int i = 0; i < 4; ++i) acc[i] = acc0[ps][i] + acc1[ps][i];
        const int p = p0 + 16 * ps + r16;

        if constexpr (EPI == 0) {              // qkv: ot64 0 = q, 64 = k, 128 = v
            const int dlo = 4 * (g & 1);
            if (ot < 64) {
                const float* qb = s ? b1 : b0;
                const float4 bv = *(const float4*)(qb + obase);
                const int h = (ot >> 3) + (g >> 1);
                half4f o = { (_Float16)((acc[0] + bv.x) * kScaleL2), (_Float16)((acc[1] + bv.y) * kScaleL2),
                             (_Float16)((acc[2] + bv.z) * kScaleL2), (_Float16)((acc[3] + bv.w) * kScaleL2) };
                *(half4f*)(o16a + (((size_t)combo * 8 + h) * kP + p) * 8 + dlo) = o;
            } else if (ot < 128) {
                const float* kb = s ? b3 : b2;
                const float4 bv = *(const float4*)(kb + obase - 64);
                const int h = ((ot - 64) >> 3) + (g >> 1);
                half4f o = { (_Float16)(acc[0] + bv.x), (_Float16)(acc[1] + bv.y),
                             (_Float16)(acc[2] + bv.z), (_Float16)(acc[3] + bv.w) };
                *(half4f*)(o16b + (((size_t)combo * 8 + h) * kP + p) * 8 + dlo) = o;
            } else {
                const float* kb = s ? b3 : b2;
                const float4 bv = *(const float4*)(kb + obase - 64);
                const int h = ((ot - 128) >> 3) + (g >> 1);
                const float* bvp = (const float*)&bv;
                #pragma unroll
                for (int i = 0; i < 4; ++i)
                    o16c[(((size_t)combo * 8 + h) * 8 + dlo + i) * kP + p] = (_Float16)(acc[i] + bvp[i]);
            }
        } else {                               // gate: sigmoid + residual -> f32 out
            const float* gb = s ? b1 : b0;
            const float4 bv = *(const float4*)(gb + obase);
            const float* bvp = (const float*)&bv;
            const half4f cx = *(const half4f*)(B + ((size_t)combo * kP + p) * 512 + 256 + obase);
            const float* F = s ? f1 : f0;
            #pragma unroll
            for (int i = 0; i < 4; ++i) {
                const int o = obase + i;
                const float gt = 1.f / (1.f + __expf(-(acc[i] + bvp[i])));
                const float fb = F[((size_t)bb * kDim + o) * kP + p];
                outp[((size_t)combo * kDim + o) * kP + p] = fb + gt * (float)cx[i];
            }
        }
    }
}

// ---------------- fused proj GEMM (K=64, M=256) + LN + Xg build.
__global__ __launch_bounds__(256) void proj_ln(
    const _Float16* __restrict__ a16, const _Float16* __restrict__ Ap,
    const float* __restrict__ pb0, const float* __restrict__ pb1,
    const float* __restrict__ w0, const float* __restrict__ b0,
    const float* __restrict__ w1, const float* __restrict__ b1,
    const float* __restrict__ f0, const float* __restrict__ f1,
    _Float16* __restrict__ Xg)
{
    __shared__ float sb[4][4][16];
    __shared__ float ssb[4][4][16];
    const int fid = blockIdx.x;
    const int xcd = fid & 7, q = fid >> 3;      // q 0..71
    const int s = (xcd >> 2) & 1, bb = (xcd >> 1) & 1, half = xcd & 1;
    const int wv = threadIdx.x >> 6, lane = threadIdx.x & 63;
    const int r16 = lane & 15, g = lane >> 4;
    const int p = half * 1152 + q * 16 + r16;
    const int combo = s * 2 + bb;
    const float* pb = s ? pb1 : pb0;
    const float* w  = s ? w1 : w0;
    const float* b  = s ? b1 : b0;
    const float* F  = s ? f1 : f0;

    const _Float16* Br = a16 + ((size_t)combo * kP + p) * 64 + 8 * g;
    const half8 bA = *(const half8*)Br;
    const half8 bB = *(const half8*)(Br + 32);
    const half4f bl0 = {bA[0], bA[1], bA[2], bA[3]};
    const half4f bh0 = {bA[4], bA[5], bA[6], bA[7]};
    const half4f bl1 = {bB[0], bB[1], bB[2], bB[3]};
    const half4f bh1 = {bB[4], bB[5], bB[6], bB[7]};

    float cval[4][4];
    float psum = 0.f, psq = 0.f;
    #pragma unroll
    for (int t = 0; t < 4; ++t) {
        const int ot = wv * 64 + t * 16;
        const _Float16* Ar = Ap + ((size_t)s * 256 + ot + r16) * 64 + 8 * g;
        const half8 aA = *(const half8*)Ar;
        const half8 aB = *(const half8*)(Ar + 32);
        const half4f al0 = {aA[0], aA[1], aA[2], aA[3]};
        const half4f ah0 = {aA[4], aA[5], aA[6], aA[7]};
        const half4f al1 = {aB[0], aB[1], aB[2], aB[3]};
        const half4f ah1 = {aB[4], aB[5], aB[6], aB[7]};
        f32x4 acc0 = __builtin_amdgcn_mfma_f32_16x16x16f16(al0, bl0, (f32x4){0.f,0.f,0.f,0.f}, 0, 0, 0);
        acc0 = __builtin_amdgcn_mfma_f32_16x16x16f16(al1, bl1, acc0, 0, 0, 0);
        f32x4 acc1 = __builtin_amdgcn_mfma_f32_16x16x16f16(ah0, bh0, (f32x4){0.f,0.f,0.f,0.f}, 0, 0, 0);
        acc1 = __builtin_amdgcn_mfma_f32_16x16x16f16(ah1, bh1, acc1, 0, 0, 0);
        const float4 bv = *(const float4*)(pb + ot + 4 * g);
        const float* bvp = (const float*)&bv;
        #pragma unroll
        for (int i = 0; i < 4; ++i) {
            const float v = acc0[i] + acc1[i] + bvp[i];
            cval[t][i] = v;
            psum += v; psq += v * v;
        }
    }
    sb[wv][g][r16] = psum; ssb[wv][g][r16] = psq;
    __syncthreads();
    float st = 0.f, sst = 0.f;
    #pragma unroll
    for (int w2 = 0; w2 < 4; ++w2)
        #pragma unroll
        for (int g2 = 0; g2 < 4; ++g2) { st += sb[w2][g2][r16]; sst += ssb[w2][g2][r16]; }
    const float mean = st * (1.f / kDim);
    const float rstd = rsqrtf(sst * (1.f / kDim) - mean * mean + kEps);

    _Float16* xrow = Xg + ((size_t)combo * kP + p) * 512;
    #pragma unroll
    for (int t = 0; t < 4; ++t) {
        const int o4 = wv * 64 + t * 16 + 4 * g;
        const float4 lw = *(const float4*)(w + o4);
        const float4 lb = *(const float4*)(b + o4);
        const float* lwp = (const float*)&lw;
        const float* lbp = (const float*)&lb;
        half4f o;
        #pragma unroll
        for (int i = 0; i < 4; ++i)
            o[i] = (_Float16)((cval[t][i] - mean) * rstd * lwp[i] + lbp[i]);
        *(half4f*)(xrow + 256 + o4) = o;
        half4f r;
        #pragma unroll
        for (int i = 0; i < 4; ++i)
            r[i] = (_Float16)F[((size_t)bb * kDim + o4 + i) * kP + p];
        *(half4f*)(xrow + o4) = r;
    }
}

// ---------------- fused MFMA flash attention, DIRECT-LOAD (no LDS, no barriers).
// Fragment layouts coincide with the global layouts of k16 (pos-major) and
// vt16 (transposed), so each lane loads its MFMA fragment straight from L2:
//   K-frag (lane r16, g<2): 8B at k16[bh][kt*16+r16][4g]   (wave: 256B contig)
//   V-frag (lane r16<8, g): 8B at vt16[bh][r16][kt*16+4g]; r16==8 -> ones (rowsum)
// exp2 softmax (Q pre-scaled by log2e), dual PV accumulators.
// grid (36, 16, 2): x = q-tile of 64, y = bh, z = stream. block 256 = 4 indep waves.
__global__ __launch_bounds__(256) void attn_mfma(
    const _Float16* __restrict__ q16, const _Float16* __restrict__ k16,
    const _Float16* __restrict__ vt16, _Float16* __restrict__ a16)
{
    const int st = blockIdx.z;
    const _Float16* Qg = q16  + (size_t)st * kInpStride;
    const _Float16* Kg = k16  + (size_t)(1 - st) * kInpStride;
    const _Float16* Vg = vt16 + (size_t)(1 - st) * kInpStride;
    const int bh = blockIdx.y;
    const int bb = bh >> 3, h = bh & 7;
    const int tid  = threadIdx.x;
    const int wv   = tid >> 6;
    const int lane = tid & 63;
    const int r16  = lane & 15;
    const int g    = lane >> 4;

    const int qg = blockIdx.x * 64 + wv * 16 + r16;
    half4f qf = (half4f){0, 0, 0, 0};
    if (g < 2) qf = *(const half4f*)(Qg + ((size_t)bh * kP + qg) * 8 + g * 4);

    const bool kact = (g < 2);
    const bool vact = (r16 < 8);
    const bool vone = (r16 == 8);
    const _Float16* kptr = Kg + ((size_t)bh * kP + r16) * 8 + (g & 1) * 4;    // +128/kt
    const _Float16* vptr = Vg + (size_t)(bh * 8 + (r16 & 7)) * kP + 4 * g;    // +16/kt
    const half4f vones = {(_Float16)1.f, (_Float16)1.f, (_Float16)1.f, (_Float16)1.f};

    f32x4 of0 = (f32x4){0.f, 0.f, 0.f, 0.f};
    f32x4 of1 = (f32x4){0.f, 0.f, 0.f, 0.f};

    #pragma unroll 4
    for (int kt = 0; kt < 144; ++kt) {
        half4f kf = (half4f){0, 0, 0, 0};
        if (kact) kf = *(const half4f*)(kptr + (size_t)kt * 128);
        half4f vf = (half4f){0, 0, 0, 0};
        if (vact) vf = *(const half4f*)(vptr + (size_t)kt * 16);
        if (vone) vf = vones;
        f32x4 sv = __builtin_amdgcn_mfma_f32_16x16x16f16(kf, qf, (f32x4){0.f,0.f,0.f,0.f}, 0, 0, 0);
        const float e0 = __builtin_amdgcn_exp2f(sv[0]);
        const float e1 = __builtin_amdgcn_exp2f(sv[1]);
        const float e2 = __builtin_amdgcn_exp2f(sv[2]);
        const float e3 = __builtin_amdgcn_exp2f(sv[3]);
        const fp16x2 lo = __builtin_amdgcn_cvt_pkrtz(e0, e1);
        const fp16x2 hi = __builtin_amdgcn_cvt_pkrtz(e2, e3);
        const half4f pf = { (_Float16)lo[0], (_Float16)lo[1],
                            (_Float16)hi[0], (_Float16)hi[1] };
        if (kt & 1) of1 = __builtin_amdgcn_mfma_f32_16x16x16f16(vf, pf, of1, 0, 0, 0);
        else        of0 = __builtin_amdgcn_mfma_f32_16x16x16f16(vf, pf, of0, 0, 0, 0);
    }
    const f32x4 of = of0 + of1;
    // rowsum lives in PV output row 8 = lanes 32..47 (g=2), reg 0
    const float rsv = __shfl(of[0], 32 + r16, 64);
    const float inv = 1.f / rsv;
    if (g < 2) {   // lane holds d = h*8 + 4g + i at position qg
        half4f o = { (_Float16)(of[0] * inv), (_Float16)(of[1] * inv),
                     (_Float16)(of[2] * inv), (_Float16)(of[3] * inv) };
        *(half4f*)(a16 + ((size_t)(st * 2 + bb) * kP + qg) * 64 + h * 8 + g * 4) = o;
    }
}

extern "C" void kernel_launch(void* const* d_in, const int* in_sizes, int n_in,
                              void* d_out, int out_size, void* d_ws, size_t ws_size,
                              hipStream_t stream)
{
    const float* f_rgb  = (const float*)d_in[0];
    const float* f_ir   = (const float*)d_in[1];
    const float* nr_w   = (const float*)d_in[2];
    const float* nr_b   = (const float*)d_in[3];
    const float* ni_w   = (const float*)d_in[4];
    const float* ni_b   = (const float*)d_in[5];
    const float* qr_w   = (const float*)d_in[6];
    const float* qr_b   = (const float*)d_in[7];
    const float* kvi_w  = (const float*)d_in[8];
    const float* kvi_b  = (const float*)d_in[9];
    const float* qi_w   = (const float*)d_in[10];
    const float* qi_b   = (const float*)d_in[11];
    const float* kvr_w  = (const float*)d_in[12];
    const float* kvr_b  = (const float*)d_in[13];
    const float* pr_w   = (const float*)d_in[14];
    const float* pr_b   = (const float*)d_in[15];
    const float* pr_lnw = (const float*)d_in[16];
    const float* pr_lnb = (const float*)d_in[17];
    const float* pi_w   = (const float*)d_in[18];
    const float* pi_b   = (const float*)d_in[19];
    const float* pi_lnw = (const float*)d_in[20];
    const float* pi_lnb = (const float*)d_in[21];
    const float* gr_w   = (const float*)d_in[22];
    const float* gr_b   = (const float*)d_in[23];
    const float* gi_w   = (const float*)d_in[24];
    const float* gi_b   = (const float*)d_in[25];

    _Float16* hb   = (_Float16*)d_ws;
    _Float16* Xq   = hb + oXq;
    _Float16* q16  = hb + oQ16;
    _Float16* k16  = hb + oK16;
    _Float16* vt16 = hb + oV16;
    _Float16* a16  = hb + oA16;
    _Float16* Xg   = hb;            // aliases [Xq|q16|k16|vt16] (dead by then)
    _Float16* W16  = hb + oW16;
    _Float16* Aq   = W16;           // [2][192][256]
    _Float16* Ap   = W16 + 98304;   // [2][256][64]
    _Float16* Ag   = W16 + 131072;  // [2][256][512]

    float* outp = (float*)d_out;
    const dim3 blk(256);

    // 1) pre-LN (XCD-affine) + weight cast in one launch
    prep<<<dim3(1088), blk, 0, stream>>>(f_rgb, nr_w, nr_b, f_ir, ni_w, ni_b, Xq,
                                         qr_w, kvr_w, qi_w, kvi_w, pr_w, pi_w, gr_w, gi_w, W16);
    // 2) qkv GEMM (M=192, K=256)
    gemm_f16<192, 256, 0><<<dim3(432), blk, 0, stream>>>(
        Aq, Xq, qr_b, qi_b, kvr_b, kvi_b, q16, k16, vt16, nullptr, nullptr, nullptr);
    // 3) fused MFMA attention -> a16 pos-major (direct-load, no LDS)
    attn_mfma<<<dim3(36, 16, 2), blk, 0, stream>>>(q16, k16, vt16, a16);
    // 4) fused proj GEMM + LN + Xg build
    proj_ln<<<dim3(576), blk, 0, stream>>>(a16, Ap, pr_b, pi_b,
                                           pr_lnw, pr_lnb, pi_lnw, pi_lnb,
                                           f_rgb, f_ir, Xg);
    // 5) gate GEMM (M=256, K=512) + sigmoid + residual -> out
    gemm_f16<256, 512, 2><<<dim3(576), blk, 0, stream>>>(
        Ag, Xg, gr_b, gi_b, nullptr, nullptr, nullptr, nullptr, nullptr, f_rgb, f_ir, outp);
}

// Round 21
// 98.494 us; speedup vs baseline: 1.4608x; 1.4608x over previous
//
#include <hip/hip_runtime.h>

static constexpr int kDim   = 256;
static constexpr int kInner = 64;
static constexpr int kNH    = 8;
static constexpr int kB     = 2;
static constexpr int kP     = 2304;   // 48*48
static constexpr float kScaleL2 = 0.5100697891920077f; // 8^-0.5 * log2(e)
static constexpr float kEps   = 1e-6f;

typedef __fp16   fp16x2 __attribute__((ext_vector_type(2)));
typedef _Float16 half4f __attribute__((ext_vector_type(4)));
typedef _Float16 half8  __attribute__((ext_vector_type(8)));
typedef float    f32x4  __attribute__((ext_vector_type(4)));

// ws layout in halfs:
static constexpr size_t oXq  = 0;          // [4 combo][2304][256]      = 2359296
static constexpr size_t oQ16 = 2359296;    // [2 inp][16 bh][2304][8]   = 589824
static constexpr size_t oK16 = 2949120;    // same                      = 589824
static constexpr size_t oV16 = 3538944;    // [2 inp][16 bh][8][2304]   = 589824
static constexpr size_t oA16 = 4128768;    // [4 combo][2304][64]       = 589824
// Xg aliases [0 .. 4718592): [4 combo][2304][512]  (written after all above dead)
static constexpr size_t oW16 = 7077888;    // weights f16               = 393216
static constexpr size_t kInpStride = 294912; // q16/k16/vt16 per-inp stride (halfs)

// ---------------- prep: blocks <576 do pre-LN (XCD-affine); blocks >=576 cast weights.
__global__ __launch_bounds__(256) void prep(
    const float* __restrict__ x0, const float* __restrict__ w0,
    const float* __restrict__ b0, const float* __restrict__ x1,
    const float* __restrict__ w1, const float* __restrict__ b1,
    _Float16* __restrict__ Xq,
    const float* __restrict__ qr_w, const float* __restrict__ kvr_w,
    const float* __restrict__ qi_w, const float* __restrict__ kvi_w,
    const float* __restrict__ pr_w, const float* __restrict__ pi_w,
    const float* __restrict__ gr_w, const float* __restrict__ gi_w,
    _Float16* __restrict__ w16)
{
    if (blockIdx.x >= 576) {               // weight cast
        const int flat = blockIdx.x - 576;
        const int y = flat >> 6, x = flat & 63;
        const float* src; _Float16* dst; int n;
        _Float16* Aq = w16;             // [2][192][256]
        _Float16* Ap = w16 + 98304;     // [2][256][64]
        _Float16* Ag = w16 + 131072;    // [2][256][512]
        switch (y) {
            case 0: src = qr_w;  dst = Aq;          n = 16384;  break;
            case 1: src = kvr_w; dst = Aq + 16384;  n = 32768;  break;
            case 2: src = qi_w;  dst = Aq + 49152;  n = 16384;  break;
            case 3: src = kvi_w; dst = Aq + 65536;  n = 32768;  break;
            case 4: src = pr_w;  dst = Ap;          n = 16384;  break;
            case 5: src = pi_w;  dst = Ap + 16384;  n = 16384;  break;
            case 6: src = gr_w;  dst = Ag;          n = 131072; break;
            default:src = gi_w;  dst = Ag + 131072; n = 131072; break;
        }
        for (int i = x * 256 + threadIdx.x; i < n; i += 64 * 256)
            dst[i] = (_Float16)src[i];
        return;
    }
    // pre-LN
    __shared__ float sb[16][16];
    __shared__ float ssb[16][16];
    const int fid = blockIdx.x;
    const int xcd = fid & 7, q = fid >> 3;      // q 0..71
    const int inp = (xcd >> 2) & 1, bb = (xcd >> 1) & 1, half = xcd & 1;
    const float* x = inp ? x1 : x0;
    const float* w = inp ? w1 : w0;
    const float* b = inp ? b1 : b0;
    const int pos = threadIdx.x & 15;
    const int grp = threadIdx.x >> 4;
    const int p   = half * 1152 + q * 16 + pos;
    const size_t base = (size_t)bb * kDim * kP + p;
    const int c0 = grp * 16;

    float v[16];
    float s = 0.f, ss = 0.f;
    #pragma unroll
    for (int j = 0; j < 16; ++j) {
        v[j] = x[base + (size_t)(c0 + j) * kP];
        s += v[j]; ss += v[j] * v[j];
    }
    sb[grp][pos] = s; ssb[grp][pos] = ss;
    __syncthreads();
    float st = 0.f, sst = 0.f;
    #pragma unroll
    for (int g = 0; g < 16; ++g) { st += sb[g][pos]; sst += ssb[g][pos]; }
    const float mean = st * (1.f / kDim);
    const float rstd = rsqrtf(sst * (1.f / kDim) - mean * mean + kEps);
    half8 h0, h1;
    #pragma unroll
    for (int j = 0; j < 8; ++j) {
        h0[j] = (_Float16)((v[j]     - mean) * rstd * w[c0 + j]     + b[c0 + j]);
        h1[j] = (_Float16)((v[j + 8] - mean) * rstd * w[c0 + j + 8] + b[c0 + j + 8]);
    }
    _Float16* dst = Xq + ((size_t)(inp * 2 + bb) * kP + p) * 256 + c0;
    *(half8*)dst       = h0;
    *(half8*)(dst + 8) = h1;
}

// ---------------- f16 MFMA GEMM, 64o x 64p block tile, 4 acc-chains per wave.
// XCD-affine flat grid: fid&7 -> (s,bb,half); fid>>3 -> (o-tile64, p-tile64).
// EPI: 0 = qkv routing (Q scaled by kScaleL2 for exp2 softmax), 2 = gate.
template <int M, int K, int EPI>
__global__ __launch_bounds__(256) void gemm_f16(
    const _Float16* __restrict__ A,     // [2][M][K] f16 weights
    const _Float16* __restrict__ B,     // [4][2304][K] f16 activations
    const float* __restrict__ b0, const float* __restrict__ b1,
    const float* __restrict__ b2, const float* __restrict__ b3,
    _Float16* __restrict__ o16a, _Float16* __restrict__ o16b, _Float16* __restrict__ o16c,
    const float* __restrict__ f0, const float* __restrict__ f1,
    float* __restrict__ outp)
{
    constexpr int MT64 = M / 64;
    const int fid = blockIdx.x;
    const int xcd = fid & 7, q = fid >> 3;
    const int s = (xcd >> 2) & 1, bb = (xcd >> 1) & 1, half = xcd & 1;
    const int ot64 = (q % MT64) * 64;
    const int pt   = q / MT64;                 // 0..17
    const int wv = threadIdx.x >> 6, lane = threadIdx.x & 63;
    const int r16 = lane & 15, g = lane >> 4;
    const int ot = ot64 + wv * 16;             // wave's 16-o tile
    const int p0 = half * 1152 + pt * 64;      // block's 64-p tile
    const int combo = s * 2 + bb;

    const _Float16* Ar = A + ((size_t)s * M + ot + r16) * K + 8 * g;
    const _Float16* Br = B + ((size_t)combo * kP + p0 + r16) * K + 8 * g;
    f32x4 acc0[4], acc1[4];
    #pragma unroll
    for (int ps = 0; ps < 4; ++ps) {
        acc0[ps] = (f32x4){0.f, 0.f, 0.f, 0.f};
        acc1[ps] = (f32x4){0.f, 0.f, 0.f, 0.f};
    }
    #pragma unroll 4
    for (int c0 = 0; c0 < K; c0 += 32) {
        const half8 a8 = *(const half8*)(Ar + c0);
        half8 b8[4];
        #pragma unroll
        for (int ps = 0; ps < 4; ++ps)
            b8[ps] = *(const half8*)(Br + (size_t)(16 * ps) * K + c0);
        const half4f al = {a8[0], a8[1], a8[2], a8[3]};
        const half4f ah = {a8[4], a8[5], a8[6], a8[7]};
        #pragma unroll
        for (int ps = 0; ps < 4; ++ps) {
            const half4f bl = {b8[ps][0], b8[ps][1], b8[ps][2], b8[ps][3]};
            const half4f bh = {b8[ps][4], b8[ps][5], b8[ps][6], b8[ps][7]};
            acc0[ps] = __builtin_amdgcn_mfma_f32_16x16x16f16(al, bl, acc0[ps], 0, 0, 0);
            acc1[ps] = __builtin_amdgcn_mfma_f32_16x16x16f16(ah, bh, acc1[ps], 0, 0, 0);
        }
    }
    const int obase = ot + 4 * g;              // o = obase + i

    #pragma unroll
    for (int ps = 0; ps < 4; ++ps) {
        float acc[4];
        #pragma unroll
        for (int i = 0; i < 4; ++i) acc[i] = acc0[ps][i] + acc1[ps][i];
        const int p = p0 + 16 * ps + r16;

        if constexpr (EPI == 0) {              // qkv: ot64 0 = q, 64 = k, 128 = v
            const int dlo = 4 * (g & 1);
            if (ot < 64) {
                const float* qb = s ? b1 : b0;
                const float4 bv = *(const float4*)(qb + obase);
                const int h = (ot >> 3) + (g >> 1);
                half4f o = { (_Float16)((acc[0] + bv.x) * kScaleL2), (_Float16)((acc[1] + bv.y) * kScaleL2),
                             (_Float16)((acc[2] + bv.z) * kScaleL2), (_Float16)((acc[3] + bv.w) * kScaleL2) };
                *(half4f*)(o16a + (((size_t)combo * 8 + h) * kP + p) * 8 + dlo) = o;
            } else if (ot < 128) {
                const float* kb = s ? b3 : b2;
                const float4 bv = *(const float4*)(kb + obase - 64);
                const int h = ((ot - 64) >> 3) + (g >> 1);
                half4f o = { (_Float16)(acc[0] + bv.x), (_Float16)(acc[1] + bv.y),
                             (_Float16)(acc[2] + bv.z), (_Float16)(acc[3] + bv.w) };
                *(half4f*)(o16b + (((size_t)combo * 8 + h) * kP + p) * 8 + dlo) = o;
            } else {
                const float* kb = s ? b3 : b2;
                const float4 bv = *(const float4*)(kb + obase - 64);
                const int h = ((ot - 128) >> 3) + (g >> 1);
                const float* bvp = (const float*)&bv;
                #pragma unroll
                for (int i = 0; i < 4; ++i)
                    o16c[(((size_t)combo * 8 + h) * 8 + dlo + i) * kP + p] = (_Float16)(acc[i] + bvp[i]);
            }
        } else {                               // gate: sigmoid + residual -> f32 out
            const float* gb = s ? b1 : b0;
            const float4 bv = *(const float4*)(gb + obase);
            const float* bvp = (const float*)&bv;
            const half4f cx = *(const half4f*)(B + ((size_t)combo * kP + p) * 512 + 256 + obase);
            const float* F = s ? f1 : f0;
            #pragma unroll
            for (int i = 0; i < 4; ++i) {
                const int o = obase + i;
                const float gt = 1.f / (1.f + __expf(-(acc[i] + bvp[i])));
                const float fb = F[((size_t)bb * kDim + o) * kP + p];
                outp[((size_t)combo * kDim + o) * kP + p] = fb + gt * (float)cx[i];
            }
        }
    }
}

// ---------------- fused proj GEMM (K=64, M=256) + LN + Xg build.
__global__ __launch_bounds__(256) void proj_ln(
    const _Float16* __restrict__ a16, const _Float16* __restrict__ Ap,
    const float* __restrict__ pb0, const float* __restrict__ pb1,
    const float* __restrict__ w0, const float* __restrict__ b0,
    const float* __restrict__ w1, const float* __restrict__ b1,
    const float* __restrict__ f0, const float* __restrict__ f1,
    _Float16* __restrict__ Xg)
{
    __shared__ float sb[4][4][16];
    __shared__ float ssb[4][4][16];
    const int fid = blockIdx.x;
    const int xcd = fid & 7, q = fid >> 3;      // q 0..71
    const int s = (xcd >> 2) & 1, bb = (xcd >> 1) & 1, half = xcd & 1;
    const int wv = threadIdx.x >> 6, lane = threadIdx.x & 63;
    const int r16 = lane & 15, g = lane >> 4;
    const int p = half * 1152 + q * 16 + r16;
    const int combo = s * 2 + bb;
    const float* pb = s ? pb1 : pb0;
    const float* w  = s ? w1 : w0;
    const float* b  = s ? b1 : b0;
    const float* F  = s ? f1 : f0;

    const _Float16* Br = a16 + ((size_t)combo * kP + p) * 64 + 8 * g;
    const half8 bA = *(const half8*)Br;
    const half8 bB = *(const half8*)(Br + 32);
    const half4f bl0 = {bA[0], bA[1], bA[2], bA[3]};
    const half4f bh0 = {bA[4], bA[5], bA[6], bA[7]};
    const half4f bl1 = {bB[0], bB[1], bB[2], bB[3]};
    const half4f bh1 = {bB[4], bB[5], bB[6], bB[7]};

    float cval[4][4];
    float psum = 0.f, psq = 0.f;
    #pragma unroll
    for (int t = 0; t < 4; ++t) {
        const int ot = wv * 64 + t * 16;
        const _Float16* Ar = Ap + ((size_t)s * 256 + ot + r16) * 64 + 8 * g;
        const half8 aA = *(const half8*)Ar;
        const half8 aB = *(const half8*)(Ar + 32);
        const half4f al0 = {aA[0], aA[1], aA[2], aA[3]};
        const half4f ah0 = {aA[4], aA[5], aA[6], aA[7]};
        const half4f al1 = {aB[0], aB[1], aB[2], aB[3]};
        const half4f ah1 = {aB[4], aB[5], aB[6], aB[7]};
        f32x4 acc0 = __builtin_amdgcn_mfma_f32_16x16x16f16(al0, bl0, (f32x4){0.f,0.f,0.f,0.f}, 0, 0, 0);
        acc0 = __builtin_amdgcn_mfma_f32_16x16x16f16(al1, bl1, acc0, 0, 0, 0);
        f32x4 acc1 = __builtin_amdgcn_mfma_f32_16x16x16f16(ah0, bh0, (f32x4){0.f,0.f,0.f,0.f}, 0, 0, 0);
        acc1 = __builtin_amdgcn_mfma_f32_16x16x16f16(ah1, bh1, acc1, 0, 0, 0);
        const float4 bv = *(const float4*)(pb + ot + 4 * g);
        const float* bvp = (const float*)&bv;
        #pragma unroll
        for (int i = 0; i < 4; ++i) {
            const float v = acc0[i] + acc1[i] + bvp[i];
            cval[t][i] = v;
            psum += v; psq += v * v;
        }
    }
    sb[wv][g][r16] = psum; ssb[wv][g][r16] = psq;
    __syncthreads();
    float st = 0.f, sst = 0.f;
    #pragma unroll
    for (int w2 = 0; w2 < 4; ++w2)
        #pragma unroll
        for (int g2 = 0; g2 < 4; ++g2) { st += sb[w2][g2][r16]; sst += ssb[w2][g2][r16]; }
    const float mean = st * (1.f / kDim);
    const float rstd = rsqrtf(sst * (1.f / kDim) - mean * mean + kEps);

    _Float16* xrow = Xg + ((size_t)combo * kP + p) * 512;
    #pragma unroll
    for (int t = 0; t < 4; ++t) {
        const int o4 = wv * 64 + t * 16 + 4 * g;
        const float4 lw = *(const float4*)(w + o4);
        const float4 lb = *(const float4*)(b + o4);
        const float* lwp = (const float*)&lw;
        const float* lbp = (const float*)&lb;
        half4f o;
        #pragma unroll
        for (int i = 0; i < 4; ++i)
            o[i] = (_Float16)((cval[t][i] - mean) * rstd * lwp[i] + lbp[i]);
        *(half4f*)(xrow + 256 + o4) = o;
        half4f r;
        #pragma unroll
        for (int i = 0; i < 4; ++i)
            r[i] = (_Float16)F[((size_t)bb * kDim + o4 + i) * kP + p];
        *(half4f*)(xrow + o4) = r;
    }
}

// ---------------- fused MFMA flash attention: frag-order LDS (V 66-slot pitch),
// single buffer + reg prefetch, dual PV accumulators, hw-exp2 softmax.
// grid (36, 16, 2): x = q-tile of 64, y = bh, z = stream. block 256 = 4 waves x 16 q.
__global__ __launch_bounds__(256) void attn_mfma(
    const _Float16* __restrict__ q16, const _Float16* __restrict__ k16,
    const _Float16* __restrict__ vt16, _Float16* __restrict__ a16)
{
    __shared__ _Float16 Ksm[16 * 64 * 4];   // [kt][slot 0..63] 8B frags (512B/kt)
    __shared__ _Float16 Vsm[16 * 66 * 4];   // [kt][slot 0..63] 8B frags, 66-slot pitch
    const int st = blockIdx.z;
    const _Float16* Qg = q16  + (size_t)st * kInpStride;
    const _Float16* Kg = k16  + (size_t)(1 - st) * kInpStride;
    const _Float16* Vg = vt16 + (size_t)(1 - st) * kInpStride;
    const int bh = blockIdx.y;
    const int bb = bh >> 3, h = bh & 7;
    const int tid  = threadIdx.x;
    const int wv   = tid >> 6;
    const int lane = tid & 63;
    const int r16  = lane & 15;
    const int g    = lane >> 4;

    // prefill static pad slots: K slots 32..63 = 0; V slots with (slot&15)>=8
    // (row 8 = ones for the rowsum trick, rows 9..15 = 0)
    #pragma unroll
    for (int j = 0; j < 2; ++j) {
        const int s = tid + 256 * j;            // 0..511
        const int kt = s >> 5, m = s & 31;
        *(half4f*)(Ksm + (kt * 64 + 32 + m) * 4) = (half4f){0, 0, 0, 0};
        const int rv = 8 + (m & 7), gv = m >> 3;
        const half4f vv = (rv == 8)
            ? (half4f){(_Float16)1.f, (_Float16)1.f, (_Float16)1.f, (_Float16)1.f}
            : (half4f){0, 0, 0, 0};
        *(half4f*)(Vsm + (kt * 66 + gv * 16 + rv) * 4) = vv;
    }

    const int qg = blockIdx.x * 64 + wv * 16 + r16;
    half4f qf = (half4f){0, 0, 0, 0};
    if (g < 2) qf = *(const half4f*)(Qg + ((size_t)bh * kP + qg) * 8 + g * 4);

    // staging coords (fixed per thread)
    const int vd = tid >> 5, vc8 = (tid & 31) * 8;
    const int vkt = vc8 >> 4, vgv = (vc8 & 15) >> 2;       // vgv in {0, 2}
    _Float16* kdst = Ksm + ((tid >> 4) * 64 + (tid & 15)) * 4;
    _Float16* vdst = Vsm + (vkt * 66 + vgv * 16 + vd) * 4;
    const _Float16* ksrc = Kg + ((size_t)bh * kP + tid) * 8;
    const _Float16* vsrc = Vg + (size_t)(bh * 8 + vd) * kP + vc8;

    // preload chunk 0
    half8 kreg = *(const half8*)ksrc;
    half8 vreg = *(const half8*)vsrc;

    f32x4 of0 = (f32x4){0.f, 0.f, 0.f, 0.f};
    f32x4 of1 = (f32x4){0.f, 0.f, 0.f, 0.f};

    for (int ch = 0; ch < 9; ++ch) {
        if (ch) __syncthreads();                // prev compute done before re-stage
        *(half4f*)kdst        = (half4f){kreg[0], kreg[1], kreg[2], kreg[3]};
        *(half4f*)(kdst + 64) = (half4f){kreg[4], kreg[5], kreg[6], kreg[7]};
        *(half4f*)vdst        = (half4f){vreg[0], vreg[1], vreg[2], vreg[3]};
        *(half4f*)(vdst + 64) = (half4f){vreg[4], vreg[5], vreg[6], vreg[7]};
        __syncthreads();
        if (ch < 8) {
            kreg = *(const half8*)(ksrc + (size_t)(ch + 1) * 2048);   // 256 keys * 8 halfs
            vreg = *(const half8*)(vsrc + (size_t)(ch + 1) * 256);    // 256 cols
        }
        #pragma unroll
        for (int kt = 0; kt < 16; ++kt) {
            const half4f kf = *(const half4f*)(Ksm + (kt * 64 + lane) * 4);
            f32x4 sv = __builtin_amdgcn_mfma_f32_16x16x16f16(kf, qf, (f32x4){0.f,0.f,0.f,0.f}, 0, 0, 0);
            const float e0 = __builtin_amdgcn_exp2f(sv[0]);
            const float e1 = __builtin_amdgcn_exp2f(sv[1]);
            const float e2 = __builtin_amdgcn_exp2f(sv[2]);
            const float e3 = __builtin_amdgcn_exp2f(sv[3]);
            const fp16x2 lo = __builtin_amdgcn_cvt_pkrtz(e0, e1);
            const fp16x2 hi = __builtin_amdgcn_cvt_pkrtz(e2, e3);
            const half4f pf = { (_Float16)lo[0], (_Float16)lo[1],
                                (_Float16)hi[0], (_Float16)hi[1] };
            const half4f vf = *(const half4f*)(Vsm + (kt * 66 + lane) * 4);
            if (kt & 1) of1 = __builtin_amdgcn_mfma_f32_16x16x16f16(vf, pf, of1, 0, 0, 0);
            else        of0 = __builtin_amdgcn_mfma_f32_16x16x16f16(vf, pf, of0, 0, 0, 0);
        }
    }
    const f32x4 of = of0 + of1;
    // rowsum lives in PV output row 8 = lane (g=2, r16), reg 0
    const float rsv = __shfl(of[0], 32 + r16, 64);
    const float inv = 1.f / rsv;
    if (g < 2) {   // lane holds d = h*8 + 4g + i at position qg
        half4f o = { (_Float16)(of[0] * inv), (_Float16)(of[1] * inv),
                     (_Float16)(of[2] * inv), (_Float16)(of[3] * inv) };
        *(half4f*)(a16 + ((size_t)(st * 2 + bb) * kP + qg) * 64 + h * 8 + g * 4) = o;
    }
}

extern "C" void kernel_launch(void* const* d_in, const int* in_sizes, int n_in,
                              void* d_out, int out_size, void* d_ws, size_t ws_size,
                              hipStream_t stream)
{
    const float* f_rgb  = (const float*)d_in[0];
    const float* f_ir   = (const float*)d_in[1];
    const float* nr_w   = (const float*)d_in[2];
    const float* nr_b   = (const float*)d_in[3];
    const float* ni_w   = (const float*)d_in[4];
    const float* ni_b   = (const float*)d_in[5];
    const float* qr_w   = (const float*)d_in[6];
    const float* qr_b   = (const float*)d_in[7];
    const float* kvi_w  = (const float*)d_in[8];
    const float* kvi_b  = (const float*)d_in[9];
    const float* qi_w   = (const float*)d_in[10];
    const float* qi_b   = (const float*)d_in[11];
    const float* kvr_w  = (const float*)d_in[12];
    const float* kvr_b  = (const float*)d_in[13];
    const float* pr_w   = (const float*)d_in[14];
    const float* pr_b   = (const float*)d_in[15];
    const float* pr_lnw = (const float*)d_in[16];
    const float* pr_lnb = (const float*)d_in[17];
    const float* pi_w   = (const float*)d_in[18];
    const float* pi_b   = (const float*)d_in[19];
    const float* pi_lnw = (const float*)d_in[20];
    const float* pi_lnb = (const float*)d_in[21];
    const float* gr_w   = (const float*)d_in[22];
    const float* gr_b   = (const float*)d_in[23];
    const float* gi_w   = (const float*)d_in[24];
    const float* gi_b   = (const float*)d_in[25];

    _Float16* hb   = (_Float16*)d_ws;
    _Float16* Xq   = hb + oXq;
    _Float16* q16  = hb + oQ16;
    _Float16* k16  = hb + oK16;
    _Float16* vt16 = hb + oV16;
    _Float16* a16  = hb + oA16;
    _Float16* Xg   = hb;            // aliases [Xq|q16|k16|vt16] (dead by then)
    _Float16* W16  = hb + oW16;
    _Float16* Aq   = W16;           // [2][192][256]
    _Float16* Ap   = W16 + 98304;   // [2][256][64]
    _Float16* Ag   = W16 + 131072;  // [2][256][512]

    float* outp = (float*)d_out;
    const dim3 blk(256);

    // 1) pre-LN (XCD-affine) + weight cast in one launch
    prep<<<dim3(1088), blk, 0, stream>>>(f_rgb, nr_w, nr_b, f_ir, ni_w, ni_b, Xq,
                                         qr_w, kvr_w, qi_w, kvi_w, pr_w, pi_w, gr_w, gi_w, W16);
    // 2) qkv GEMM (M=192, K=256)
    gemm_f16<192, 256, 0><<<dim3(432), blk, 0, stream>>>(
        Aq, Xq, qr_b, qi_b, kvr_b, kvi_b, q16, k16, vt16, nullptr, nullptr, nullptr);
    // 3) fused MFMA attention -> a16 pos-major
    attn_mfma<<<dim3(36, 16, 2), blk, 0, stream>>>(q16, k16, vt16, a16);
    // 4) fused proj GEMM + LN + Xg build
    proj_ln<<<dim3(576), blk, 0, stream>>>(a16, Ap, pr_b, pi_b,
                                           pr_lnw, pr_lnb, pi_lnw, pi_lnb,
                                           f_rgb, f_ir, Xg);
    // 5) gate GEMM (M=256, K=512) + sigmoid + residual -> out
    gemm_f16<256, 512, 2><<<dim3(576), blk, 0, stream>>>(
        Ag, Xg, gr_b, gi_b, nullptr, nullptr, nullptr, nullptr, nullptr, f_rgb, f_ir, outp);
}

// Round 22
// 97.942 us; speedup vs baseline: 1.4691x; 1.0056x over previous
//
#include <hip/hip_runtime.h>

static constexpr int kDim   = 256;
static constexpr int kInner = 64;
static constexpr int kNH    = 8;
static constexpr int kB     = 2;
static constexpr int kP     = 2304;   // 48*48
static constexpr float kScaleL2 = 0.5100697891920077f; // 8^-0.5 * log2(e)
static constexpr float kEps   = 1e-6f;

typedef __fp16   fp16x2 __attribute__((ext_vector_type(2)));
typedef _Float16 half4f __attribute__((ext_vector_type(4)));
typedef _Float16 half8  __attribute__((ext_vector_type(8)));
typedef float    f32x4  __attribute__((ext_vector_type(4)));

// ws layout in halfs:
static constexpr size_t oXq  = 0;          // [4 combo][2304][256]      = 2359296
static constexpr size_t oQ16 = 2359296;    // [2 inp][16 bh][2304][8]   = 589824
static constexpr size_t oK16 = 2949120;    // same                      = 589824
static constexpr size_t oV16 = 3538944;    // [2 inp][16 bh][8][2304]   = 589824
static constexpr size_t oA16 = 4128768;    // [4 combo][2304][64]       = 589824
// Xg aliases [0 .. 4718592): [4 combo][2304][512]  (written after all above dead)
static constexpr size_t oW16 = 7077888;    // weights f16               = 393216
static constexpr size_t kInpStride = 294912; // q16/k16/vt16 per-inp stride (halfs)

// ---------------- prep: blocks <576 do pre-LN (XCD-affine); blocks >=576 cast weights.
__global__ __launch_bounds__(256) void prep(
    const float* __restrict__ x0, const float* __restrict__ w0,
    const float* __restrict__ b0, const float* __restrict__ x1,
    const float* __restrict__ w1, const float* __restrict__ b1,
    _Float16* __restrict__ Xq,
    const float* __restrict__ qr_w, const float* __restrict__ kvr_w,
    const float* __restrict__ qi_w, const float* __restrict__ kvi_w,
    const float* __restrict__ pr_w, const float* __restrict__ pi_w,
    const float* __restrict__ gr_w, const float* __restrict__ gi_w,
    _Float16* __restrict__ w16)
{
    if (blockIdx.x >= 576) {               // weight cast
        const int flat = blockIdx.x - 576;
        const int y = flat >> 6, x = flat & 63;
        const float* src; _Float16* dst; int n;
        _Float16* Aq = w16;             // [2][192][256]
        _Float16* Ap = w16 + 98304;     // [2][256][64]
        _Float16* Ag = w16 + 131072;    // [2][256][512]
        switch (y) {
            case 0: src = qr_w;  dst = Aq;          n = 16384;  break;
            case 1: src = kvr_w; dst = Aq + 16384;  n = 32768;  break;
            case 2: src = qi_w;  dst = Aq + 49152;  n = 16384;  break;
            case 3: src = kvi_w; dst = Aq + 65536;  n = 32768;  break;
            case 4: src = pr_w;  dst = Ap;          n = 16384;  break;
            case 5: src = pi_w;  dst = Ap + 16384;  n = 16384;  break;
            case 6: src = gr_w;  dst = Ag;          n = 131072; break;
            default:src = gi_w;  dst = Ag + 131072; n = 131072; break;
        }
        for (int i = x * 256 + threadIdx.x; i < n; i += 64 * 256)
            dst[i] = (_Float16)src[i];
        return;
    }
    // pre-LN
    __shared__ float sb[16][16];
    __shared__ float ssb[16][16];
    const int fid = blockIdx.x;
    const int xcd = fid & 7, q = fid >> 3;      // q 0..71
    const int inp = (xcd >> 2) & 1, bb = (xcd >> 1) & 1, half = xcd & 1;
    const float* x = inp ? x1 : x0;
    const float* w = inp ? w1 : w0;
    const float* b = inp ? b1 : b0;
    const int pos = threadIdx.x & 15;
    const int grp = threadIdx.x >> 4;
    const int p   = half * 1152 + q * 16 + pos;
    const size_t base = (size_t)bb * kDim * kP + p;
    const int c0 = grp * 16;

    float v[16];
    float s = 0.f, ss = 0.f;
    #pragma unroll
    for (int j = 0; j < 16; ++j) {
        v[j] = x[base + (size_t)(c0 + j) * kP];
        s += v[j]; ss += v[j] * v[j];
    }
    sb[grp][pos] = s; ssb[grp][pos] = ss;
    __syncthreads();
    float st = 0.f, sst = 0.f;
    #pragma unroll
    for (int g = 0; g < 16; ++g) { st += sb[g][pos]; sst += ssb[g][pos]; }
    const float mean = st * (1.f / kDim);
    const float rstd = rsqrtf(sst * (1.f / kDim) - mean * mean + kEps);
    half8 h0, h1;
    #pragma unroll
    for (int j = 0; j < 8; ++j) {
        h0[j] = (_Float16)((v[j]     - mean) * rstd * w[c0 + j]     + b[c0 + j]);
        h1[j] = (_Float16)((v[j + 8] - mean) * rstd * w[c0 + j + 8] + b[c0 + j + 8]);
    }
    _Float16* dst = Xq + ((size_t)(inp * 2 + bb) * kP + p) * 256 + c0;
    *(half8*)dst       = h0;
    *(half8*)(dst + 8) = h1;
}

// ---------------- f16 MFMA GEMM, 64o x 64p block tile, 4 acc-chains per wave.
// XCD-affine flat grid: fid&7 -> (s,bb,half); fid>>3 -> (o-tile64, p-tile64).
// EPI: 0 = qkv routing (Q scaled by kScaleL2 for exp2 softmax), 2 = gate.
template <int M, int K, int EPI>
__global__ __launch_bounds__(256) void gemm_f16(
    const _Float16* __restrict__ A,     // [2][M][K] f16 weights
    const _Float16* __restrict__ B,     // [4][2304][K] f16 activations
    const float* __restrict__ b0, const float* __restrict__ b1,
    const float* __restrict__ b2, const float* __restrict__ b3,
    _Float16* __restrict__ o16a, _Float16* __restrict__ o16b, _Float16* __restrict__ o16c,
    const float* __restrict__ f0, const float* __restrict__ f1,
    float* __restrict__ outp)
{
    constexpr int MT64 = M / 64;
    const int fid = blockIdx.x;
    const int xcd = fid & 7, q = fid >> 3;
    const int s = (xcd >> 2) & 1, bb = (xcd >> 1) & 1, half = xcd & 1;
    const int ot64 = (q % MT64) * 64;
    const int pt   = q / MT64;                 // 0..17
    const int wv = threadIdx.x >> 6, lane = threadIdx.x & 63;
    const int r16 = lane & 15, g = lane >> 4;
    const int ot = ot64 + wv * 16;             // wave's 16-o tile
    const int p0 = half * 1152 + pt * 64;      // block's 64-p tile
    const int combo = s * 2 + bb;

    const _Float16* Ar = A + ((size_t)s * M + ot + r16) * K + 8 * g;
    const _Float16* Br = B + ((size_t)combo * kP + p0 + r16) * K + 8 * g;
    f32x4 acc0[4], acc1[4];
    #pragma unroll
    for (int ps = 0; ps < 4; ++ps) {
        acc0[ps] = (f32x4){0.f, 0.f, 0.f, 0.f};
        acc1[ps] = (f32x4){0.f, 0.f, 0.f, 0.f};
    }
    #pragma unroll 4
    for (int c0 = 0; c0 < K; c0 += 32) {
        const half8 a8 = *(const half8*)(Ar + c0);
        half8 b8[4];
        #pragma unroll
        for (int ps = 0; ps < 4; ++ps)
            b8[ps] = *(const half8*)(Br + (size_t)(16 * ps) * K + c0);
        const half4f al = {a8[0], a8[1], a8[2], a8[3]};
        const half4f ah = {a8[4], a8[5], a8[6], a8[7]};
        #pragma unroll
        for (int ps = 0; ps < 4; ++ps) {
            const half4f bl = {b8[ps][0], b8[ps][1], b8[ps][2], b8[ps][3]};
            const half4f bh = {b8[ps][4], b8[ps][5], b8[ps][6], b8[ps][7]};
            acc0[ps] = __builtin_amdgcn_mfma_f32_16x16x16f16(al, bl, acc0[ps], 0, 0, 0);
            acc1[ps] = __builtin_amdgcn_mfma_f32_16x16x16f16(ah, bh, acc1[ps], 0, 0, 0);
        }
    }
    const int obase = ot + 4 * g;              // o = obase + i

    #pragma unroll
    for (int ps = 0; ps < 4; ++ps) {
        float acc[4];
        #pragma unroll
        for (int i = 0; i < 4; ++i) acc[i] = acc0[ps][i] + acc1[ps][i];
        const int p = p0 + 16 * ps + r16;

        if constexpr (EPI == 0) {              // qkv: ot64 0 = q, 64 = k, 128 = v
            const int dlo = 4 * (g & 1);
            if (ot < 64) {
                const float* qb = s ? b1 : b0;
                const float4 bv = *(const float4*)(qb + obase);
                const int h = (ot >> 3) + (g >> 1);
                half4f o = { (_Float16)((acc[0] + bv.x) * kScaleL2), (_Float16)((acc[1] + bv.y) * kScaleL2),
                             (_Float16)((acc[2] + bv.z) * kScaleL2), (_Float16)((acc[3] + bv.w) * kScaleL2) };
                *(half4f*)(o16a + (((size_t)combo * 8 + h) * kP + p) * 8 + dlo) = o;
            } else if (ot < 128) {
                const float* kb = s ? b3 : b2;
                const float4 bv = *(const float4*)(kb + obase - 64);
                const int h = ((ot - 64) >> 3) + (g >> 1);
                half4f o = { (_Float16)(acc[0] + bv.x), (_Float16)(acc[1] + bv.y),
                             (_Float16)(acc[2] + bv.z), (_Float16)(acc[3] + bv.w) };
                *(half4f*)(o16b + (((size_t)combo * 8 + h) * kP + p) * 8 + dlo) = o;
            } else {
                const float* kb = s ? b3 : b2;
                const float4 bv = *(const float4*)(kb + obase - 64);
                const int h = ((ot - 128) >> 3) + (g >> 1);
                const float* bvp = (const float*)&bv;
                #pragma unroll
                for (int i = 0; i < 4; ++i)
                    o16c[(((size_t)combo * 8 + h) * 8 + dlo + i) * kP + p] = (_Float16)(acc[i] + bvp[i]);
            }
        } else {                               // gate: sigmoid + residual -> f32 out
            const float* gb = s ? b1 : b0;
            const float4 bv = *(const float4*)(gb + obase);
            const float* bvp = (const float*)&bv;
            const half4f cx = *(const half4f*)(B + ((size_t)combo * kP + p) * 512 + 256 + obase);
            const float* F = s ? f1 : f0;
            #pragma unroll
            for (int i = 0; i < 4; ++i) {
                const int o = obase + i;
                const float gt = 1.f / (1.f + __expf(-(acc[i] + bvp[i])));
                const float fb = F[((size_t)bb * kDim + o) * kP + p];
                outp[((size_t)combo * kDim + o) * kP + p] = fb + gt * (float)cx[i];
            }
        }
    }
}

// ---------------- fused proj GEMM (K=64, M=256) + LN + Xg build.
__global__ __launch_bounds__(256) void proj_ln(
    const _Float16* __restrict__ a16, const _Float16* __restrict__ Ap,
    const float* __restrict__ pb0, const float* __restrict__ pb1,
    const float* __restrict__ w0, const float* __restrict__ b0,
    const float* __restrict__ w1, const float* __restrict__ b1,
    const float* __restrict__ f0, const float* __restrict__ f1,
    _Float16* __restrict__ Xg)
{
    __shared__ float sb[4][4][16];
    __shared__ float ssb[4][4][16];
    const int fid = blockIdx.x;
    const int xcd = fid & 7, q = fid >> 3;      // q 0..71
    const int s = (xcd >> 2) & 1, bb = (xcd >> 1) & 1, half = xcd & 1;
    const int wv = threadIdx.x >> 6, lane = threadIdx.x & 63;
    const int r16 = lane & 15, g = lane >> 4;
    const int p = half * 1152 + q * 16 + r16;
    const int combo = s * 2 + bb;
    const float* pb = s ? pb1 : pb0;
    const float* w  = s ? w1 : w0;
    const float* b  = s ? b1 : b0;
    const float* F  = s ? f1 : f0;

    const _Float16* Br = a16 + ((size_t)combo * kP + p) * 64 + 8 * g;
    const half8 bA = *(const half8*)Br;
    const half8 bB = *(const half8*)(Br + 32);
    const half4f bl0 = {bA[0], bA[1], bA[2], bA[3]};
    const half4f bh0 = {bA[4], bA[5], bA[6], bA[7]};
    const half4f bl1 = {bB[0], bB[1], bB[2], bB[3]};
    const half4f bh1 = {bB[4], bB[5], bB[6], bB[7]};

    float cval[4][4];
    float psum = 0.f, psq = 0.f;
    #pragma unroll
    for (int t = 0; t < 4; ++t) {
        const int ot = wv * 64 + t * 16;
        const _Float16* Ar = Ap + ((size_t)s * 256 + ot + r16) * 64 + 8 * g;
        const half8 aA = *(const half8*)Ar;
        const half8 aB = *(const half8*)(Ar + 32);
        const half4f al0 = {aA[0], aA[1], aA[2], aA[3]};
        const half4f ah0 = {aA[4], aA[5], aA[6], aA[7]};
        const half4f al1 = {aB[0], aB[1], aB[2], aB[3]};
        const half4f ah1 = {aB[4], aB[5], aB[6], aB[7]};
        f32x4 acc0 = __builtin_amdgcn_mfma_f32_16x16x16f16(al0, bl0, (f32x4){0.f,0.f,0.f,0.f}, 0, 0, 0);
        acc0 = __builtin_amdgcn_mfma_f32_16x16x16f16(al1, bl1, acc0, 0, 0, 0);
        f32x4 acc1 = __builtin_amdgcn_mfma_f32_16x16x16f16(ah0, bh0, (f32x4){0.f,0.f,0.f,0.f}, 0, 0, 0);
        acc1 = __builtin_amdgcn_mfma_f32_16x16x16f16(ah1, bh1, acc1, 0, 0, 0);
        const float4 bv = *(const float4*)(pb + ot + 4 * g);
        const float* bvp = (const float*)&bv;
        #pragma unroll
        for (int i = 0; i < 4; ++i) {
            const float v = acc0[i] + acc1[i] + bvp[i];
            cval[t][i] = v;
            psum += v; psq += v * v;
        }
    }
    sb[wv][g][r16] = psum; ssb[wv][g][r16] = psq;
    __syncthreads();
    float st = 0.f, sst = 0.f;
    #pragma unroll
    for (int w2 = 0; w2 < 4; ++w2)
        #pragma unroll
        for (int g2 = 0; g2 < 4; ++g2) { st += sb[w2][g2][r16]; sst += ssb[w2][g2][r16]; }
    const float mean = st * (1.f / kDim);
    const float rstd = rsqrtf(sst * (1.f / kDim) - mean * mean + kEps);

    _Float16* xrow = Xg + ((size_t)combo * kP + p) * 512;
    #pragma unroll
    for (int t = 0; t < 4; ++t) {
        const int o4 = wv * 64 + t * 16 + 4 * g;
        const float4 lw = *(const float4*)(w + o4);
        const float4 lb = *(const float4*)(b + o4);
        const float* lwp = (const float*)&lw;
        const float* lbp = (const float*)&lb;
        half4f o;
        #pragma unroll
        for (int i = 0; i < 4; ++i)
            o[i] = (_Float16)((cval[t][i] - mean) * rstd * lwp[i] + lbp[i]);
        *(half4f*)(xrow + 256 + o4) = o;
        half4f r;
        #pragma unroll
        for (int i = 0; i < 4; ++i)
            r[i] = (_Float16)F[((size_t)bb * kDim + o4 + i) * kP + p];
        *(half4f*)(xrow + o4) = r;
    }
}

// ---------------- fused MFMA flash attention: 8 waves / 128 q per block.
// Frag-order LDS (V 66-slot pitch) shared by all 8 waves; staging split:
// tid<256 stages K (one 16B load), tid>=256 stages V. Reg prefetch, dual PV
// accumulators, hw-exp2 softmax.
// grid (18, 16, 2): x = q-tile of 128, y = bh, z = stream. block 512 = 8 waves.
__global__ __launch_bounds__(512) void attn_mfma(
    const _Float16* __restrict__ q16, const _Float16* __restrict__ k16,
    const _Float16* __restrict__ vt16, _Float16* __restrict__ a16)
{
    __shared__ _Float16 Ksm[16 * 64 * 4];   // [kt][slot 0..63] 8B frags (512B/kt)
    __shared__ _Float16 Vsm[16 * 66 * 4];   // [kt][slot 0..63] 8B frags, 66-slot pitch
    const int st = blockIdx.z;
    const _Float16* Qg = q16  + (size_t)st * kInpStride;
    const _Float16* Kg = k16  + (size_t)(1 - st) * kInpStride;
    const _Float16* Vg = vt16 + (size_t)(1 - st) * kInpStride;
    const int bh = blockIdx.y;
    const int bb = bh >> 3, h = bh & 7;
    const int tid  = threadIdx.x;
    const int wv   = tid >> 6;              // 0..7
    const int lane = tid & 63;
    const int r16  = lane & 15;
    const int g    = lane >> 4;

    // prefill static pad slots (512 threads cover all 512 K-pad + 512 V-pad slots)
    {
        const int s = tid;                  // 0..511
        const int kt = s >> 5, m = s & 31;
        *(half4f*)(Ksm + (kt * 64 + 32 + m) * 4) = (half4f){0, 0, 0, 0};
        const int rv = 8 + (m & 7), gv = m >> 3;
        const half4f vv = (rv == 8)
            ? (half4f){(_Float16)1.f, (_Float16)1.f, (_Float16)1.f, (_Float16)1.f}
            : (half4f){0, 0, 0, 0};
        *(half4f*)(Vsm + (kt * 66 + gv * 16 + rv) * 4) = vv;
    }

    const int qg = blockIdx.x * 128 + wv * 16 + r16;
    half4f qf = (half4f){0, 0, 0, 0};
    if (g < 2) qf = *(const half4f*)(Qg + ((size_t)bh * kP + qg) * 8 + g * 4);

    // staging role: tid<256 -> K key tid; tid>=256 -> V (d, 8 cols)
    const bool isK = (tid < 256);
    const int svt = tid & 255;
    const int vd = svt >> 5, vc8 = (svt & 31) * 8;
    const int vkt = vc8 >> 4, vgv = (vc8 & 15) >> 2;       // vgv in {0, 2}
    _Float16* sdst = isK ? (Ksm + ((svt >> 4) * 64 + (svt & 15)) * 4)
                         : (Vsm + (vkt * 66 + vgv * 16 + vd) * 4);
    const _Float16* ssrc = isK ? (Kg + ((size_t)bh * kP + svt) * 8)
                               : (Vg + (size_t)(bh * 8 + vd) * kP + vc8);
    const size_t sstep = isK ? 2048 : 256;   // halfs per 256-key chunk

    // preload chunk 0
    half8 sreg = *(const half8*)ssrc;

    f32x4 of0 = (f32x4){0.f, 0.f, 0.f, 0.f};
    f32x4 of1 = (f32x4){0.f, 0.f, 0.f, 0.f};

    for (int ch = 0; ch < 9; ++ch) {
        if (ch) __syncthreads();                // prev compute done before re-stage
        *(half4f*)sdst        = (half4f){sreg[0], sreg[1], sreg[2], sreg[3]};
        *(half4f*)(sdst + 64) = (half4f){sreg[4], sreg[5], sreg[6], sreg[7]};
        __syncthreads();
        if (ch < 8) sreg = *(const half8*)(ssrc + (size_t)(ch + 1) * sstep);
        #pragma unroll
        for (int kt = 0; kt < 16; ++kt) {
            const half4f kf = *(const half4f*)(Ksm + (kt * 64 + lane) * 4);
            f32x4 sv = __builtin_amdgcn_mfma_f32_16x16x16f16(kf, qf, (f32x4){0.f,0.f,0.f,0.f}, 0, 0, 0);
            const float e0 = __builtin_amdgcn_exp2f(sv[0]);
            const float e1 = __builtin_amdgcn_exp2f(sv[1]);
            const float e2 = __builtin_amdgcn_exp2f(sv[2]);
            const float e3 = __builtin_amdgcn_exp2f(sv[3]);
            const fp16x2 lo = __builtin_amdgcn_cvt_pkrtz(e0, e1);
            const fp16x2 hi = __builtin_amdgcn_cvt_pkrtz(e2, e3);
            const half4f pf = { (_Float16)lo[0], (_Float16)lo[1],
                                (_Float16)hi[0], (_Float16)hi[1] };
            const half4f vf = *(const half4f*)(Vsm + (kt * 66 + lane) * 4);
            if (kt & 1) of1 = __builtin_amdgcn_mfma_f32_16x16x16f16(vf, pf, of1, 0, 0, 0);
            else        of0 = __builtin_amdgcn_mfma_f32_16x16x16f16(vf, pf, of0, 0, 0, 0);
        }
    }
    const f32x4 of = of0 + of1;
    // rowsum lives in PV output row 8 = lane (g=2, r16), reg 0
    const float rsv = __shfl(of[0], 32 + r16, 64);
    const float inv = 1.f / rsv;
    if (g < 2) {   // lane holds d = h*8 + 4g + i at position qg
        half4f o = { (_Float16)(of[0] * inv), (_Float16)(of[1] * inv),
                     (_Float16)(of[2] * inv), (_Float16)(of[3] * inv) };
        *(half4f*)(a16 + ((size_t)(st * 2 + bb) * kP + qg) * 64 + h * 8 + g * 4) = o;
    }
}

extern "C" void kernel_launch(void* const* d_in, const int* in_sizes, int n_in,
                              void* d_out, int out_size, void* d_ws, size_t ws_size,
                              hipStream_t stream)
{
    const float* f_rgb  = (const float*)d_in[0];
    const float* f_ir   = (const float*)d_in[1];
    const float* nr_w   = (const float*)d_in[2];
    const float* nr_b   = (const float*)d_in[3];
    const float* ni_w   = (const float*)d_in[4];
    const float* ni_b   = (const float*)d_in[5];
    const float* qr_w   = (const float*)d_in[6];
    const float* qr_b   = (const float*)d_in[7];
    const float* kvi_w  = (const float*)d_in[8];
    const float* kvi_b  = (const float*)d_in[9];
    const float* qi_w   = (const float*)d_in[10];
    const float* qi_b   = (const float*)d_in[11];
    const float* kvr_w  = (const float*)d_in[12];
    const float* kvr_b  = (const float*)d_in[13];
    const float* pr_w   = (const float*)d_in[14];
    const float* pr_b   = (const float*)d_in[15];
    const float* pr_lnw = (const float*)d_in[16];
    const float* pr_lnb = (const float*)d_in[17];
    const float* pi_w   = (const float*)d_in[18];
    const float* pi_b   = (const float*)d_in[19];
    const float* pi_lnw = (const float*)d_in[20];
    const float* pi_lnb = (const float*)d_in[21];
    const float* gr_w   = (const float*)d_in[22];
    const float* gr_b   = (const float*)d_in[23];
    const float* gi_w   = (const float*)d_in[24];
    const float* gi_b   = (const float*)d_in[25];

    _Float16* hb   = (_Float16*)d_ws;
    _Float16* Xq   = hb + oXq;
    _Float16* q16  = hb + oQ16;
    _Float16* k16  = hb + oK16;
    _Float16* vt16 = hb + oV16;
    _Float16* a16  = hb + oA16;
    _Float16* Xg   = hb;            // aliases [Xq|q16|k16|vt16] (dead by then)
    _Float16* W16  = hb + oW16;
    _Float16* Aq   = W16;           // [2][192][256]
    _Float16* Ap   = W16 + 98304;   // [2][256][64]
    _Float16* Ag   = W16 + 131072;  // [2][256][512]

    float* outp = (float*)d_out;
    const dim3 blk(256);

    // 1) pre-LN (XCD-affine) + weight cast in one launch
    prep<<<dim3(1088), blk, 0, stream>>>(f_rgb, nr_w, nr_b, f_ir, ni_w, ni_b, Xq,
                                         qr_w, kvr_w, qi_w, kvi_w, pr_w, pi_w, gr_w, gi_w, W16);
    // 2) qkv GEMM (M=192, K=256)
    gemm_f16<192, 256, 0><<<dim3(432), blk, 0, stream>>>(
        Aq, Xq, qr_b, qi_b, kvr_b, kvi_b, q16, k16, vt16, nullptr, nullptr, nullptr);
    // 3) fused MFMA attention -> a16 pos-major (8 waves / 128 q per block)
    attn_mfma<<<dim3(18, 16, 2), dim3(512), 0, stream>>>(q16, k16, vt16, a16);
    // 4) fused proj GEMM + LN + Xg build
    proj_ln<<<dim3(576), blk, 0, stream>>>(a16, Ap, pr_b, pi_b,
                                           pr_lnw, pr_lnb, pi_lnw, pi_lnb,
                                           f_rgb, f_ir, Xg);
    // 5) gate GEMM (M=256, K=512) + sigmoid + residual -> out
    gemm_f16<256, 512, 2><<<dim3(576), blk, 0, stream>>>(
        Ag, Xg, gr_b, gi_b, nullptr, nullptr, nullptr, nullptr, nullptr, f_rgb, f_ir, outp);
}

// Round 23
// 97.253 us; speedup vs baseline: 1.4795x; 1.0071x over previous
//
#include <hip/hip_runtime.h>

static constexpr int kDim   = 256;
static constexpr int kInner = 64;
static constexpr int kNH    = 8;
static constexpr int kB     = 2;
static constexpr int kP     = 2304;   // 48*48
static constexpr float kScaleL2 = 0.5100697891920077f; // 8^-0.5 * log2(e)
static constexpr float kEps   = 1e-6f;

typedef __fp16   fp16x2 __attribute__((ext_vector_type(2)));
typedef _Float16 half4f __attribute__((ext_vector_type(4)));
typedef _Float16 half8  __attribute__((ext_vector_type(8)));
typedef float    f32x4  __attribute__((ext_vector_type(4)));

// ws layout in halfs:
static constexpr size_t oXq  = 0;          // [4 combo][2304][256]      = 2359296
static constexpr size_t oQ16 = 2359296;    // [2 inp][16 bh][2304][8]   = 589824
static constexpr size_t oK16 = 2949120;    // same                      = 589824
static constexpr size_t oV16 = 3538944;    // [2 inp][16 bh][8][2304]   = 589824
static constexpr size_t oA16 = 4128768;    // [4 combo][2304][64]       = 589824
// Xg aliases [0 .. 4718592): [4 combo][2304][512]  (written after all above dead)
static constexpr size_t oW16 = 7077888;    // weights f16               = 393216
static constexpr size_t kInpStride = 294912; // q16/k16/vt16 per-inp stride (halfs)

// ---------------- prep: blocks <576 do pre-LN (XCD-affine); blocks >=576 cast weights.
__global__ __launch_bounds__(256) void prep(
    const float* __restrict__ x0, const float* __restrict__ w0,
    const float* __restrict__ b0, const float* __restrict__ x1,
    const float* __restrict__ w1, const float* __restrict__ b1,
    _Float16* __restrict__ Xq,
    const float* __restrict__ qr_w, const float* __restrict__ kvr_w,
    const float* __restrict__ qi_w, const float* __restrict__ kvi_w,
    const float* __restrict__ pr_w, const float* __restrict__ pi_w,
    const float* __restrict__ gr_w, const float* __restrict__ gi_w,
    _Float16* __restrict__ w16)
{
    if (blockIdx.x >= 576) {               // weight cast
        const int flat = blockIdx.x - 576;
        const int y = flat >> 6, x = flat & 63;
        const float* src; _Float16* dst; int n;
        _Float16* Aq = w16;             // [2][192][256]
        _Float16* Ap = w16 + 98304;     // [2][256][64]
        _Float16* Ag = w16 + 131072;    // [2][256][512]
        switch (y) {
            case 0: src = qr_w;  dst = Aq;          n = 16384;  break;
            case 1: src = kvr_w; dst = Aq + 16384;  n = 32768;  break;
            case 2: src = qi_w;  dst = Aq + 49152;  n = 16384;  break;
            case 3: src = kvi_w; dst = Aq + 65536;  n = 32768;  break;
            case 4: src = pr_w;  dst = Ap;          n = 16384;  break;
            case 5: src = pi_w;  dst = Ap + 16384;  n = 16384;  break;
            case 6: src = gr_w;  dst = Ag;          n = 131072; break;
            default:src = gi_w;  dst = Ag + 131072; n = 131072; break;
        }
        for (int i = x * 256 + threadIdx.x; i < n; i += 64 * 256)
            dst[i] = (_Float16)src[i];
        return;
    }
    // pre-LN
    __shared__ float sb[16][16];
    __shared__ float ssb[16][16];
    const int fid = blockIdx.x;
    const int xcd = fid & 7, q = fid >> 3;      // q 0..71
    const int inp = (xcd >> 2) & 1, bb = (xcd >> 1) & 1, half = xcd & 1;
    const float* x = inp ? x1 : x0;
    const float* w = inp ? w1 : w0;
    const float* b = inp ? b1 : b0;
    const int pos = threadIdx.x & 15;
    const int grp = threadIdx.x >> 4;
    const int p   = half * 1152 + q * 16 + pos;
    const size_t base = (size_t)bb * kDim * kP + p;
    const int c0 = grp * 16;

    float v[16];
    float s = 0.f, ss = 0.f;
    #pragma unroll
    for (int j = 0; j < 16; ++j) {
        v[j] = x[base + (size_t)(c0 + j) * kP];
        s += v[j]; ss += v[j] * v[j];
    }
    sb[grp][pos] = s; ssb[grp][pos] = ss;
    __syncthreads();
    float st = 0.f, sst = 0.f;
    #pragma unroll
    for (int g = 0; g < 16; ++g) { st += sb[g][pos]; sst += ssb[g][pos]; }
    const float mean = st * (1.f / kDim);
    const float rstd = rsqrtf(sst * (1.f / kDim) - mean * mean + kEps);
    half8 h0, h1;
    #pragma unroll
    for (int j = 0; j < 8; ++j) {
        h0[j] = (_Float16)((v[j]     - mean) * rstd * w[c0 + j]     + b[c0 + j]);
        h1[j] = (_Float16)((v[j + 8] - mean) * rstd * w[c0 + j + 8] + b[c0 + j + 8]);
    }
    _Float16* dst = Xq + ((size_t)(inp * 2 + bb) * kP + p) * 256 + c0;
    *(half8*)dst       = h0;
    *(half8*)(dst + 8) = h1;
}

// ---------------- f16 MFMA GEMM, 64o x 64p block tile, 4 acc-chains per wave.
// XCD-affine flat grid: fid&7 -> (s,bb,half); fid>>3 -> (o-tile64, p-tile64).
// EPI: 0 = qkv routing (Q scaled by kScaleL2 for exp2 softmax), 2 = gate.
template <int M, int K, int EPI>
__global__ __launch_bounds__(256) void gemm_f16(
    const _Float16* __restrict__ A,     // [2][M][K] f16 weights
    const _Float16* __restrict__ B,     // [4][2304][K] f16 activations
    const float* __restrict__ b0, const float* __restrict__ b1,
    const float* __restrict__ b2, const float* __restrict__ b3,
    _Float16* __restrict__ o16a, _Float16* __restrict__ o16b, _Float16* __restrict__ o16c,
    const float* __restrict__ f0, const float* __restrict__ f1,
    float* __restrict__ outp)
{
    constexpr int MT64 = M / 64;
    const int fid = blockIdx.x;
    const int xcd = fid & 7, q = fid >> 3;
    const int s = (xcd >> 2) & 1, bb = (xcd >> 1) & 1, half = xcd & 1;
    const int ot64 = (q % MT64) * 64;
    const int pt   = q / MT64;                 // 0..17
    const int wv = threadIdx.x >> 6, lane = threadIdx.x & 63;
    const int r16 = lane & 15, g = lane >> 4;
    const int ot = ot64 + wv * 16;             // wave's 16-o tile
    const int p0 = half * 1152 + pt * 64;      // block's 64-p tile
    const int combo = s * 2 + bb;

    const _Float16* Ar = A + ((size_t)s * M + ot + r16) * K + 8 * g;
    const _Float16* Br = B + ((size_t)combo * kP + p0 + r16) * K + 8 * g;
    f32x4 acc0[4], acc1[4];
    #pragma unroll
    for (int ps = 0; ps < 4; ++ps) {
        acc0[ps] = (f32x4){0.f, 0.f, 0.f, 0.f};
        acc1[ps] = (f32x4){0.f, 0.f, 0.f, 0.f};
    }
    #pragma unroll 4
    for (int c0 = 0; c0 < K; c0 += 32) {
        const half8 a8 = *(const half8*)(Ar + c0);
        half8 b8[4];
        #pragma unroll
        for (int ps = 0; ps < 4; ++ps)
            b8[ps] = *(const half8*)(Br + (size_t)(16 * ps) * K + c0);
        const half4f al = {a8[0], a8[1], a8[2], a8[3]};
        const half4f ah = {a8[4], a8[5], a8[6], a8[7]};
        #pragma unroll
        for (int ps = 0; ps < 4; ++ps) {
            const half4f bl = {b8[ps][0], b8[ps][1], b8[ps][2], b8[ps][3]};
            const half4f bh = {b8[ps][4], b8[ps][5], b8[ps][6], b8[ps][7]};
            acc0[ps] = __builtin_amdgcn_mfma_f32_16x16x16f16(al, bl, acc0[ps], 0, 0, 0);
            acc1[ps] = __builtin_amdgcn_mfma_f32_16x16x16f16(ah, bh, acc1[ps], 0, 0, 0);
        }
    }
    const int obase = ot + 4 * g;              // o = obase + i

    #pragma unroll
    for (int ps = 0; ps < 4; ++ps) {
        float acc[4];
        #pragma unroll
        for (int i = 0; i < 4; ++i) acc[i] = acc0[ps][i] + acc1[ps][i];
        const int p = p0 + 16 * ps + r16;

        if constexpr (EPI == 0) {              // qkv: ot64 0 = q, 64 = k, 128 = v
            const int dlo = 4 * (g & 1);
            if (ot < 64) {
                const float* qb = s ? b1 : b0;
                const float4 bv = *(const float4*)(qb + obase);
                const int h = (ot >> 3) + (g >> 1);
                half4f o = { (_Float16)((acc[0] + bv.x) * kScaleL2), (_Float16)((acc[1] + bv.y) * kScaleL2),
                             (_Float16)((acc[2] + bv.z) * kScaleL2), (_Float16)((acc[3] + bv.w) * kScaleL2) };
                *(half4f*)(o16a + (((size_t)combo * 8 + h) * kP + p) * 8 + dlo) = o;
            } else if (ot < 128) {
                const float* kb = s ? b3 : b2;
                const float4 bv = *(const float4*)(kb + obase - 64);
                const int h = ((ot - 64) >> 3) + (g >> 1);
                half4f o = { (_Float16)(acc[0] + bv.x), (_Float16)(acc[1] + bv.y),
                             (_Float16)(acc[2] + bv.z), (_Float16)(acc[3] + bv.w) };
                *(half4f*)(o16b + (((size_t)combo * 8 + h) * kP + p) * 8 + dlo) = o;
            } else {
                const float* kb = s ? b3 : b2;
                const float4 bv = *(const float4*)(kb + obase - 64);
                const int h = ((ot - 128) >> 3) + (g >> 1);
                const float* bvp = (const float*)&bv;
                #pragma unroll
                for (int i = 0; i < 4; ++i)
                    o16c[(((size_t)combo * 8 + h) * 8 + dlo + i) * kP + p] = (_Float16)(acc[i] + bvp[i]);
            }
        } else {                               // gate: sigmoid + residual -> f32 out
            const float* gb = s ? b1 : b0;
            const float4 bv = *(const float4*)(gb + obase);
            const float* bvp = (const float*)&bv;
            const half4f cx = *(const half4f*)(B + ((size_t)combo * kP + p) * 512 + 256 + obase);
            const float* F = s ? f1 : f0;
            #pragma unroll
            for (int i = 0; i < 4; ++i) {
                const int o = obase + i;
                const float gt = 1.f / (1.f + __expf(-(acc[i] + bvp[i])));
                const float fb = F[((size_t)bb * kDim + o) * kP + p];
                outp[((size_t)combo * kDim + o) * kP + p] = fb + gt * (float)cx[i];
            }
        }
    }
}

// ---------------- fused proj GEMM (K=64, M=256) + LN + Xg build.
__global__ __launch_bounds__(256) void proj_ln(
    const _Float16* __restrict__ a16, const _Float16* __restrict__ Ap,
    const float* __restrict__ pb0, const float* __restrict__ pb1,
    const float* __restrict__ w0, const float* __restrict__ b0,
    const float* __restrict__ w1, const float* __restrict__ b1,
    const float* __restrict__ f0, const float* __restrict__ f1,
    _Float16* __restrict__ Xg)
{
    __shared__ float sb[4][4][16];
    __shared__ float ssb[4][4][16];
    const int fid = blockIdx.x;
    const int xcd = fid & 7, q = fid >> 3;      // q 0..71
    const int s = (xcd >> 2) & 1, bb = (xcd >> 1) & 1, half = xcd & 1;
    const int wv = threadIdx.x >> 6, lane = threadIdx.x & 63;
    const int r16 = lane & 15, g = lane >> 4;
    const int p = half * 1152 + q * 16 + r16;
    const int combo = s * 2 + bb;
    const float* pb = s ? pb1 : pb0;
    const float* w  = s ? w1 : w0;
    const float* b  = s ? b1 : b0;
    const float* F  = s ? f1 : f0;

    const _Float16* Br = a16 + ((size_t)combo * kP + p) * 64 + 8 * g;
    const half8 bA = *(const half8*)Br;
    const half8 bB = *(const half8*)(Br + 32);
    const half4f bl0 = {bA[0], bA[1], bA[2], bA[3]};
    const half4f bh0 = {bA[4], bA[5], bA[6], bA[7]};
    const half4f bl1 = {bB[0], bB[1], bB[2], bB[3]};
    const half4f bh1 = {bB[4], bB[5], bB[6], bB[7]};

    float cval[4][4];
    float psum = 0.f, psq = 0.f;
    #pragma unroll
    for (int t = 0; t < 4; ++t) {
        const int ot = wv * 64 + t * 16;
        const _Float16* Ar = Ap + ((size_t)s * 256 + ot + r16) * 64 + 8 * g;
        const half8 aA = *(const half8*)Ar;
        const half8 aB = *(const half8*)(Ar + 32);
        const half4f al0 = {aA[0], aA[1], aA[2], aA[3]};
        const half4f ah0 = {aA[4], aA[5], aA[6], aA[7]};
        const half4f al1 = {aB[0], aB[1], aB[2], aB[3]};
        const half4f ah1 = {aB[4], aB[5], aB[6], aB[7]};
        f32x4 acc0 = __builtin_amdgcn_mfma_f32_16x16x16f16(al0, bl0, (f32x4){0.f,0.f,0.f,0.f}, 0, 0, 0);
        acc0 = __builtin_amdgcn_mfma_f32_16x16x16f16(al1, bl1, acc0, 0, 0, 0);
        f32x4 acc1 = __builtin_amdgcn_mfma_f32_16x16x16f16(ah0, bh0, (f32x4){0.f,0.f,0.f,0.f}, 0, 0, 0);
        acc1 = __builtin_amdgcn_mfma_f32_16x16x16f16(ah1, bh1, acc1, 0, 0, 0);
        const float4 bv = *(const float4*)(pb + ot + 4 * g);
        const float* bvp = (const float*)&bv;
        #pragma unroll
        for (int i = 0; i < 4; ++i) {
            const float v = acc0[i] + acc1[i] + bvp[i];
            cval[t][i] = v;
            psum += v; psq += v * v;
        }
    }
    sb[wv][g][r16] = psum; ssb[wv][g][r16] = psq;
    __syncthreads();
    float st = 0.f, sst = 0.f;
    #pragma unroll
    for (int w2 = 0; w2 < 4; ++w2)
        #pragma unroll
        for (int g2 = 0; g2 < 4; ++g2) { st += sb[w2][g2][r16]; sst += ssb[w2][g2][r16]; }
    const float mean = st * (1.f / kDim);
    const float rstd = rsqrtf(sst * (1.f / kDim) - mean * mean + kEps);

    _Float16* xrow = Xg + ((size_t)combo * kP + p) * 512;
    #pragma unroll
    for (int t = 0; t < 4; ++t) {
        const int o4 = wv * 64 + t * 16 + 4 * g;
        const float4 lw = *(const float4*)(w + o4);
        const float4 lb = *(const float4*)(b + o4);
        const float* lwp = (const float*)&lw;
        const float* lbp = (const float*)&lb;
        half4f o;
        #pragma unroll
        for (int i = 0; i < 4; ++i)
            o[i] = (_Float16)((cval[t][i] - mean) * rstd * lwp[i] + lbp[i]);
        *(half4f*)(xrow + 256 + o4) = o;
        half4f r;
        #pragma unroll
        for (int i = 0; i < 4; ++i)
            r[i] = (_Float16)F[((size_t)bb * kDim + o4 + i) * kP + p];
        *(half4f*)(xrow + o4) = r;
    }
}

// ---------------- fused MFMA flash attention: 8 waves / 128 q per block,
// DOUBLE-BUFFERED frag-order LDS (V 66-slot pitch), ONE barrier per chunk.
// Staging split: tid<256 stages K, tid>=256 stages V (one 16B load each).
// Dual PV accumulators, hw-exp2 softmax.
// grid (18, 16, 2): x = q-tile of 128, y = bh, z = stream. block 512 = 8 waves.
__global__ __launch_bounds__(512) void attn_mfma(
    const _Float16* __restrict__ q16, const _Float16* __restrict__ k16,
    const _Float16* __restrict__ vt16, _Float16* __restrict__ a16)
{
    __shared__ _Float16 Ksm[2][16 * 64 * 4];   // per buf: [kt][slot] 8B frags
    __shared__ _Float16 Vsm[2][16 * 66 * 4];   // per buf: 66-slot pitch
    const int st = blockIdx.z;
    const _Float16* Qg = q16  + (size_t)st * kInpStride;
    const _Float16* Kg = k16  + (size_t)(1 - st) * kInpStride;
    const _Float16* Vg = vt16 + (size_t)(1 - st) * kInpStride;
    const int bh = blockIdx.y;
    const int bb = bh >> 3, h = bh & 7;
    const int tid  = threadIdx.x;
    const int wv   = tid >> 6;              // 0..7
    const int lane = tid & 63;
    const int r16  = lane & 15;
    const int g    = lane >> 4;

    // prefill static pad slots of BOTH buffers (512 threads x 2 bufs)
    #pragma unroll
    for (int j = 0; j < 2; ++j) {
        const int s = tid;                  // 0..511
        const int kt = s >> 5, m = s & 31;
        *(half4f*)(Ksm[j] + (kt * 64 + 32 + m) * 4) = (half4f){0, 0, 0, 0};
        const int rv = 8 + (m & 7), gv = m >> 3;
        const half4f vvp = (rv == 8)
            ? (half4f){(_Float16)1.f, (_Float16)1.f, (_Float16)1.f, (_Float16)1.f}
            : (half4f){0, 0, 0, 0};
        *(half4f*)(Vsm[j] + (kt * 66 + gv * 16 + rv) * 4) = vvp;
    }

    const int qg = blockIdx.x * 128 + wv * 16 + r16;
    half4f qf = (half4f){0, 0, 0, 0};
    if (g < 2) qf = *(const half4f*)(Qg + ((size_t)bh * kP + qg) * 8 + g * 4);

    // staging role: tid<256 -> K key tid; tid>=256 -> V (d, 8 cols)
    const bool isK = (tid < 256);
    const int svt = tid & 255;
    const int vd = svt >> 5, vc8 = (svt & 31) * 8;
    const int vkt = vc8 >> 4, vgv = (vc8 & 15) >> 2;       // vgv in {0, 2}
    const int soff = isK ? (((svt >> 4) * 64 + (svt & 15)) * 4)
                         : ((vkt * 66 + vgv * 16 + vd) * 4);
    const _Float16* ssrc = isK ? (Kg + ((size_t)bh * kP + svt) * 8)
                               : (Vg + (size_t)(bh * 8 + vd) * kP + vc8);
    const size_t sstep = isK ? 2048 : 256;   // halfs per 256-key chunk

    // preload + write chunk 0 into buffer 0
    {
        const half8 s0 = *(const half8*)ssrc;
        _Float16* d0 = (isK ? Ksm[0] : Vsm[0]) + soff;
        *(half4f*)d0        = (half4f){s0[0], s0[1], s0[2], s0[3]};
        *(half4f*)(d0 + 64) = (half4f){s0[4], s0[5], s0[6], s0[7]};
    }

    f32x4 of0 = (f32x4){0.f, 0.f, 0.f, 0.f};
    f32x4 of1 = (f32x4){0.f, 0.f, 0.f, 0.f};

    for (int ch = 0; ch < 9; ++ch) {
        __syncthreads();                        // buf[ch&1] fully written
        half8 sreg;
        if (ch < 8) sreg = *(const half8*)(ssrc + (size_t)(ch + 1) * sstep);
        const _Float16* Kb = Ksm[ch & 1];
        const _Float16* Vb = Vsm[ch & 1];
        #pragma unroll
        for (int kt = 0; kt < 16; ++kt) {
            const half4f kf = *(const half4f*)(Kb + (kt * 64 + lane) * 4);
            f32x4 sv = __builtin_amdgcn_mfma_f32_16x16x16f16(kf, qf, (f32x4){0.f,0.f,0.f,0.f}, 0, 0, 0);
            const float e0 = __builtin_amdgcn_exp2f(sv[0]);
            const float e1 = __builtin_amdgcn_exp2f(sv[1]);
            const float e2 = __builtin_amdgcn_exp2f(sv[2]);
            const float e3 = __builtin_amdgcn_exp2f(sv[3]);
            const fp16x2 lo = __builtin_amdgcn_cvt_pkrtz(e0, e1);
            const fp16x2 hi = __builtin_amdgcn_cvt_pkrtz(e2, e3);
            const half4f pf = { (_Float16)lo[0], (_Float16)lo[1],
                                (_Float16)hi[0], (_Float16)hi[1] };
            const half4f vf = *(const half4f*)(Vb + (kt * 66 + lane) * 4);
            if (kt & 1) of1 = __builtin_amdgcn_mfma_f32_16x16x16f16(vf, pf, of1, 0, 0, 0);
            else        of0 = __builtin_amdgcn_mfma_f32_16x16x16f16(vf, pf, of0, 0, 0, 0);
        }
        if (ch < 8) {                           // write next chunk to other buffer
            _Float16* dn = (isK ? Ksm[(ch + 1) & 1] : Vsm[(ch + 1) & 1]) + soff;
            *(half4f*)dn        = (half4f){sreg[0], sreg[1], sreg[2], sreg[3]};
            *(half4f*)(dn + 64) = (half4f){sreg[4], sreg[5], sreg[6], sreg[7]};
        }
    }
    const f32x4 of = of0 + of1;
    // rowsum lives in PV output row 8 = lane (g=2, r16), reg 0
    const float rsv = __shfl(of[0], 32 + r16, 64);
    const float inv = 1.f / rsv;
    if (g < 2) {   // lane holds d = h*8 + 4g + i at position qg
        half4f o = { (_Float16)(of[0] * inv), (_Float16)(of[1] * inv),
                     (_Float16)(of[2] * inv), (_Float16)(of[3] * inv) };
        *(half4f*)(a16 + ((size_t)(st * 2 + bb) * kP + qg) * 64 + h * 8 + g * 4) = o;
    }
}

extern "C" void kernel_launch(void* const* d_in, const int* in_sizes, int n_in,
                              void* d_out, int out_size, void* d_ws, size_t ws_size,
                              hipStream_t stream)
{
    const float* f_rgb  = (const float*)d_in[0];
    const float* f_ir   = (const float*)d_in[1];
    const float* nr_w   = (const float*)d_in[2];
    const float* nr_b   = (const float*)d_in[3];
    const float* ni_w   = (const float*)d_in[4];
    const float* ni_b   = (const float*)d_in[5];
    const float* qr_w   = (const float*)d_in[6];
    const float* qr_b   = (const float*)d_in[7];
    const float* kvi_w  = (const float*)d_in[8];
    const float* kvi_b  = (const float*)d_in[9];
    const float* qi_w   = (const float*)d_in[10];
    const float* qi_b   = (const float*)d_in[11];
    const float* kvr_w  = (const float*)d_in[12];
    const float* kvr_b  = (const float*)d_in[13];
    const float* pr_w   = (const float*)d_in[14];
    const float* pr_b   = (const float*)d_in[15];
    const float* pr_lnw = (const float*)d_in[16];
    const float* pr_lnb = (const float*)d_in[17];
    const float* pi_w   = (const float*)d_in[18];
    const float* pi_b   = (const float*)d_in[19];
    const float* pi_lnw = (const float*)d_in[20];
    const float* pi_lnb = (const float*)d_in[21];
    const float* gr_w   = (const float*)d_in[22];
    const float* gr_b   = (const float*)d_in[23];
    const float* gi_w   = (const float*)d_in[24];
    const float* gi_b   = (const float*)d_in[25];

    _Float16* hb   = (_Float16*)d_ws;
    _Float16* Xq   = hb + oXq;
    _Float16* q16  = hb + oQ16;
    _Float16* k16  = hb + oK16;
    _Float16* vt16 = hb + oV16;
    _Float16* a16  = hb + oA16;
    _Float16* Xg   = hb;            // aliases [Xq|q16|k16|vt16] (dead by then)
    _Float16* W16  = hb + oW16;
    _Float16* Aq   = W16;           // [2][192][256]
    _Float16* Ap   = W16 + 98304;   // [2][256][64]
    _Float16* Ag   = W16 + 131072;  // [2][256][512]

    float* outp = (float*)d_out;
    const dim3 blk(256);

    // 1) pre-LN (XCD-affine) + weight cast in one launch
    prep<<<dim3(1088), blk, 0, stream>>>(f_rgb, nr_w, nr_b, f_ir, ni_w, ni_b, Xq,
                                         qr_w, kvr_w, qi_w, kvi_w, pr_w, pi_w, gr_w, gi_w, W16);
    // 2) qkv GEMM (M=192, K=256)
    gemm_f16<192, 256, 0><<<dim3(432), blk, 0, stream>>>(
        Aq, Xq, qr_b, qi_b, kvr_b, kvi_b, q16, k16, vt16, nullptr, nullptr, nullptr);
    // 3) fused MFMA attention -> a16 pos-major (8 waves, double-buffered)
    attn_mfma<<<dim3(18, 16, 2), dim3(512), 0, stream>>>(q16, k16, vt16, a16);
    // 4) fused proj GEMM + LN + Xg build
    proj_ln<<<dim3(576), blk, 0, stream>>>(a16, Ap, pr_b, pi_b,
                                           pr_lnw, pr_lnb, pi_lnw, pi_lnb,
                                           f_rgb, f_ir, Xg);
    // 5) gate GEMM (M=256, K=512) + sigmoid + residual -> out
    gemm_f16<256, 512, 2><<<dim3(576), blk, 0, stream>>>(
        Ag, Xg, gr_b, gi_b, nullptr, nullptr, nullptr, nullptr, nullptr, f_rgb, f_ir, outp);
}

// Round 24
// 96.659 us; speedup vs baseline: 1.4885x; 1.0061x over previous
//
#include <hip/hip_runtime.h>

static constexpr int kDim   = 256;
static constexpr int kInner = 64;
static constexpr int kNH    = 8;
static constexpr int kB     = 2;
static constexpr int kP     = 2304;   // 48*48
static constexpr float kScaleL2 = 0.5100697891920077f; // 8^-0.5 * log2(e)
static constexpr float kEps   = 1e-6f;

typedef __fp16   fp16x2 __attribute__((ext_vector_type(2)));
typedef _Float16 half4f __attribute__((ext_vector_type(4)));
typedef _Float16 half8  __attribute__((ext_vector_type(8)));
typedef float    f32x4  __attribute__((ext_vector_type(4)));

// ws layout in halfs:
static constexpr size_t oXq  = 0;          // [4 combo][2304][256]      = 2359296
static constexpr size_t oQ16 = 2359296;    // [2 inp][16 bh][2304][8]   = 589824
static constexpr size_t oK16 = 2949120;    // same                      = 589824
static constexpr size_t oV16 = 3538944;    // [2 inp][16 bh][8][2304]   = 589824
static constexpr size_t oA16 = 4128768;    // [4 combo][2304][64]       = 589824
// Xg aliases [0 .. 4718592): [4 combo][2304][512]  (written after all above dead)
static constexpr size_t oW16 = 7077888;    // weights f16               = 393216
static constexpr size_t kInpStride = 294912; // q16/k16/vt16 per-inp stride (halfs)

// ---------------- prep: blocks <576 do pre-LN (XCD-affine); blocks >=576 cast weights.
__global__ __launch_bounds__(256) void prep(
    const float* __restrict__ x0, const float* __restrict__ w0,
    const float* __restrict__ b0, const float* __restrict__ x1,
    const float* __restrict__ w1, const float* __restrict__ b1,
    _Float16* __restrict__ Xq,
    const float* __restrict__ qr_w, const float* __restrict__ kvr_w,
    const float* __restrict__ qi_w, const float* __restrict__ kvi_w,
    const float* __restrict__ pr_w, const float* __restrict__ pi_w,
    const float* __restrict__ gr_w, const float* __restrict__ gi_w,
    _Float16* __restrict__ w16)
{
    if (blockIdx.x >= 576) {               // weight cast
        const int flat = blockIdx.x - 576;
        const int y = flat >> 6, x = flat & 63;
        const float* src; _Float16* dst; int n;
        _Float16* Aq = w16;             // [2][192][256]
        _Float16* Ap = w16 + 98304;     // [2][256][64]
        _Float16* Ag = w16 + 131072;    // [2][256][512]
        switch (y) {
            case 0: src = qr_w;  dst = Aq;          n = 16384;  break;
            case 1: src = kvr_w; dst = Aq + 16384;  n = 32768;  break;
            case 2: src = qi_w;  dst = Aq + 49152;  n = 16384;  break;
            case 3: src = kvi_w; dst = Aq + 65536;  n = 32768;  break;
            case 4: src = pr_w;  dst = Ap;          n = 16384;  break;
            case 5: src = pi_w;  dst = Ap + 16384;  n = 16384;  break;
            case 6: src = gr_w;  dst = Ag;          n = 131072; break;
            default:src = gi_w;  dst = Ag + 131072; n = 131072; break;
        }
        for (int i = x * 256 + threadIdx.x; i < n; i += 64 * 256)
            dst[i] = (_Float16)src[i];
        return;
    }
    // pre-LN
    __shared__ float sb[16][16];
    __shared__ float ssb[16][16];
    const int fid = blockIdx.x;
    const int xcd = fid & 7, q = fid >> 3;      // q 0..71
    const int inp = (xcd >> 2) & 1, bb = (xcd >> 1) & 1, half = xcd & 1;
    const float* x = inp ? x1 : x0;
    const float* w = inp ? w1 : w0;
    const float* b = inp ? b1 : b0;
    const int pos = threadIdx.x & 15;
    const int grp = threadIdx.x >> 4;
    const int p   = half * 1152 + q * 16 + pos;
    const size_t base = (size_t)bb * kDim * kP + p;
    const int c0 = grp * 16;

    float v[16];
    float s = 0.f, ss = 0.f;
    #pragma unroll
    for (int j = 0; j < 16; ++j) {
        v[j] = x[base + (size_t)(c0 + j) * kP];
        s += v[j]; ss += v[j] * v[j];
    }
    sb[grp][pos] = s; ssb[grp][pos] = ss;
    __syncthreads();
    float st = 0.f, sst = 0.f;
    #pragma unroll
    for (int g = 0; g < 16; ++g) { st += sb[g][pos]; sst += ssb[g][pos]; }
    const float mean = st * (1.f / kDim);
    const float rstd = rsqrtf(sst * (1.f / kDim) - mean * mean + kEps);
    half8 h0, h1;
    #pragma unroll
    for (int j = 0; j < 8; ++j) {
        h0[j] = (_Float16)((v[j]     - mean) * rstd * w[c0 + j]     + b[c0 + j]);
        h1[j] = (_Float16)((v[j + 8] - mean) * rstd * w[c0 + j + 8] + b[c0 + j + 8]);
    }
    _Float16* dst = Xq + ((size_t)(inp * 2 + bb) * kP + p) * 256 + c0;
    *(half8*)dst       = h0;
    *(half8*)(dst + 8) = h1;
}

// ---------------- f16 MFMA GEMM, 64o x 64p block tile, 4 acc-chains per wave.
// XCD-affine flat grid: fid&7 -> (s,bb,half); fid>>3 -> (o-tile64, p-tile64).
// EPI: 0 = qkv routing (Q scaled by kScaleL2 for exp2 softmax), 2 = gate.
template <int M, int K, int EPI>
__global__ __launch_bounds__(256) void gemm_f16(
    const _Float16* __restrict__ A,     // [2][M][K] f16 weights
    const _Float16* __restrict__ B,     // [4][2304][K] f16 activations
    const float* __restrict__ b0, const float* __restrict__ b1,
    const float* __restrict__ b2, const float* __restrict__ b3,
    _Float16* __restrict__ o16a, _Float16* __restrict__ o16b, _Float16* __restrict__ o16c,
    const float* __restrict__ f0, const float* __restrict__ f1,
    float* __restrict__ outp)
{
    constexpr int MT64 = M / 64;
    const int fid = blockIdx.x;
    const int xcd = fid & 7, q = fid >> 3;
    const int s = (xcd >> 2) & 1, bb = (xcd >> 1) & 1, half = xcd & 1;
    const int ot64 = (q % MT64) * 64;
    const int pt   = q / MT64;                 // 0..17
    const int wv = threadIdx.x >> 6, lane = threadIdx.x & 63;
    const int r16 = lane & 15, g = lane >> 4;
    const int ot = ot64 + wv * 16;             // wave's 16-o tile
    const int p0 = half * 1152 + pt * 64;      // block's 64-p tile
    const int combo = s * 2 + bb;

    const _Float16* Ar = A + ((size_t)s * M + ot + r16) * K + 8 * g;
    const _Float16* Br = B + ((size_t)combo * kP + p0 + r16) * K + 8 * g;
    f32x4 acc0[4], acc1[4];
    #pragma unroll
    for (int ps = 0; ps < 4; ++ps) {
        acc0[ps] = (f32x4){0.f, 0.f, 0.f, 0.f};
        acc1[ps] = (f32x4){0.f, 0.f, 0.f, 0.f};
    }
    #pragma unroll 4
    for (int c0 = 0; c0 < K; c0 += 32) {
        const half8 a8 = *(const half8*)(Ar + c0);
        half8 b8[4];
        #pragma unroll
        for (int ps = 0; ps < 4; ++ps)
            b8[ps] = *(const half8*)(Br + (size_t)(16 * ps) * K + c0);
        const half4f al = {a8[0], a8[1], a8[2], a8[3]};
        const half4f ah = {a8[4], a8[5], a8[6], a8[7]};
        #pragma unroll
        for (int ps = 0; ps < 4; ++ps) {
            const half4f bl = {b8[ps][0], b8[ps][1], b8[ps][2], b8[ps][3]};
            const half4f bh = {b8[ps][4], b8[ps][5], b8[ps][6], b8[ps][7]};
            acc0[ps] = __builtin_amdgcn_mfma_f32_16x16x16f16(al, bl, acc0[ps], 0, 0, 0);
            acc1[ps] = __builtin_amdgcn_mfma_f32_16x16x16f16(ah, bh, acc1[ps], 0, 0, 0);
        }
    }
    const int obase = ot + 4 * g;              // o = obase + i

    #pragma unroll
    for (int ps = 0; ps < 4; ++ps) {
        float acc[4];
        #pragma unroll
        for (int i = 0; i < 4; ++i) acc[i] = acc0[ps][i] + acc1[ps][i];
        const int p = p0 + 16 * ps + r16;

        if constexpr (EPI == 0) {              // qkv: ot64 0 = q, 64 = k, 128 = v
            const int dlo = 4 * (g & 1);
            if (ot < 64) {
                const float* qb = s ? b1 : b0;
                const float4 bv = *(const float4*)(qb + obase);
                const int h = (ot >> 3) + (g >> 1);
                half4f o = { (_Float16)((acc[0] + bv.x) * kScaleL2), (_Float16)((acc[1] + bv.y) * kScaleL2),
                             (_Float16)((acc[2] + bv.z) * kScaleL2), (_Float16)((acc[3] + bv.w) * kScaleL2) };
                *(half4f*)(o16a + (((size_t)combo * 8 + h) * kP + p) * 8 + dlo) = o;
            } else if (ot < 128) {
                const float* kb = s ? b3 : b2;
                const float4 bv = *(const float4*)(kb + obase - 64);
                const int h = ((ot - 64) >> 3) + (g >> 1);
                half4f o = { (_Float16)(acc[0] + bv.x), (_Float16)(acc[1] + bv.y),
                             (_Float16)(acc[2] + bv.z), (_Float16)(acc[3] + bv.w) };
                *(half4f*)(o16b + (((size_t)combo * 8 + h) * kP + p) * 8 + dlo) = o;
            } else {
                const float* kb = s ? b3 : b2;
                const float4 bv = *(const float4*)(kb + obase - 64);
                const int h = ((ot - 128) >> 3) + (g >> 1);
                const float* bvp = (const float*)&bv;
                #pragma unroll
                for (int i = 0; i < 4; ++i)
                    o16c[(((size_t)combo * 8 + h) * 8 + dlo + i) * kP + p] = (_Float16)(acc[i] + bvp[i]);
            }
        } else {                               // gate: sigmoid + residual -> f32 out
            const float* gb = s ? b1 : b0;
            const float4 bv = *(const float4*)(gb + obase);
            const float* bvp = (const float*)&bv;
            const half4f cx = *(const half4f*)(B + ((size_t)combo * kP + p) * 512 + 256 + obase);
            const float* F = s ? f1 : f0;
            #pragma unroll
            for (int i = 0; i < 4; ++i) {
                const int o = obase + i;
                const float gt = 1.f / (1.f + __expf(-(acc[i] + bvp[i])));
                const float fb = F[((size_t)bb * kDim + o) * kP + p];
                outp[((size_t)combo * kDim + o) * kP + p] = fb + gt * (float)cx[i];
            }
        }
    }
}

// ---------------- fused proj GEMM (K=64, M=256) + LN + Xg build.
__global__ __launch_bounds__(256) void proj_ln(
    const _Float16* __restrict__ a16, const _Float16* __restrict__ Ap,
    const float* __restrict__ pb0, const float* __restrict__ pb1,
    const float* __restrict__ w0, const float* __restrict__ b0,
    const float* __restrict__ w1, const float* __restrict__ b1,
    const float* __restrict__ f0, const float* __restrict__ f1,
    _Float16* __restrict__ Xg)
{
    __shared__ float sb[4][4][16];
    __shared__ float ssb[4][4][16];
    const int fid = blockIdx.x;
    const int xcd = fid & 7, q = fid >> 3;      // q 0..71
    const int s = (xcd >> 2) & 1, bb = (xcd >> 1) & 1, half = xcd & 1;
    const int wv = threadIdx.x >> 6, lane = threadIdx.x & 63;
    const int r16 = lane & 15, g = lane >> 4;
    const int p = half * 1152 + q * 16 + r16;
    const int combo = s * 2 + bb;
    const float* pb = s ? pb1 : pb0;
    const float* w  = s ? w1 : w0;
    const float* b  = s ? b1 : b0;
    const float* F  = s ? f1 : f0;

    const _Float16* Br = a16 + ((size_t)combo * kP + p) * 64 + 8 * g;
    const half8 bA = *(const half8*)Br;
    const half8 bB = *(const half8*)(Br + 32);
    const half4f bl0 = {bA[0], bA[1], bA[2], bA[3]};
    const half4f bh0 = {bA[4], bA[5], bA[6], bA[7]};
    const half4f bl1 = {bB[0], bB[1], bB[2], bB[3]};
    const half4f bh1 = {bB[4], bB[5], bB[6], bB[7]};

    float cval[4][4];
    float psum = 0.f, psq = 0.f;
    #pragma unroll
    for (int t = 0; t < 4; ++t) {
        const int ot = wv * 64 + t * 16;
        const _Float16* Ar = Ap + ((size_t)s * 256 + ot + r16) * 64 + 8 * g;
        const half8 aA = *(const half8*)Ar;
        const half8 aB = *(const half8*)(Ar + 32);
        const half4f al0 = {aA[0], aA[1], aA[2], aA[3]};
        const half4f ah0 = {aA[4], aA[5], aA[6], aA[7]};
        const half4f al1 = {aB[0], aB[1], aB[2], aB[3]};
        const half4f ah1 = {aB[4], aB[5], aB[6], aB[7]};
        f32x4 acc0 = __builtin_amdgcn_mfma_f32_16x16x16f16(al0, bl0, (f32x4){0.f,0.f,0.f,0.f}, 0, 0, 0);
        acc0 = __builtin_amdgcn_mfma_f32_16x16x16f16(al1, bl1, acc0, 0, 0, 0);
        f32x4 acc1 = __builtin_amdgcn_mfma_f32_16x16x16f16(ah0, bh0, (f32x4){0.f,0.f,0.f,0.f}, 0, 0, 0);
        acc1 = __builtin_amdgcn_mfma_f32_16x16x16f16(ah1, bh1, acc1, 0, 0, 0);
        const float4 bv = *(const float4*)(pb + ot + 4 * g);
        const float* bvp = (const float*)&bv;
        #pragma unroll
        for (int i = 0; i < 4; ++i) {
            const float v = acc0[i] + acc1[i] + bvp[i];
            cval[t][i] = v;
            psum += v; psq += v * v;
        }
    }
    sb[wv][g][r16] = psum; ssb[wv][g][r16] = psq;
    __syncthreads();
    float st = 0.f, sst = 0.f;
    #pragma unroll
    for (int w2 = 0; w2 < 4; ++w2)
        #pragma unroll
        for (int g2 = 0; g2 < 4; ++g2) { st += sb[w2][g2][r16]; sst += ssb[w2][g2][r16]; }
    const float mean = st * (1.f / kDim);
    const float rstd = rsqrtf(sst * (1.f / kDim) - mean * mean + kEps);

    _Float16* xrow = Xg + ((size_t)combo * kP + p) * 512;
    #pragma unroll
    for (int t = 0; t < 4; ++t) {
        const int o4 = wv * 64 + t * 16 + 4 * g;
        const float4 lw = *(const float4*)(w + o4);
        const float4 lb = *(const float4*)(b + o4);
        const float* lwp = (const float*)&lw;
        const float* lbp = (const float*)&lb;
        half4f o;
        #pragma unroll
        for (int i = 0; i < 4; ++i)
            o[i] = (_Float16)((cval[t][i] - mean) * rstd * lwp[i] + lbp[i]);
        *(half4f*)(xrow + 256 + o4) = o;
        half4f r;
        #pragma unroll
        for (int i = 0; i < 4; ++i)
            r[i] = (_Float16)F[((size_t)bb * kDim + o4 + i) * kP + p];
        *(half4f*)(xrow + o4) = r;
    }
}

// ---------------- fused MFMA flash attention: 8 waves / 128 q, double-buffered
// PAIRED-kt LDS: frag(kt, slot) at (kt>>1)*PAIR + slot*8 + (kt&1)*4 halfs, so a
// single ds_read_b128 at kt2*PAIR + lane*8 yields both even and odd kt frags
// (lane-sequential 16B -> conflict-free). K PAIR=512, V PAIR=528 (16-half pad).
// One barrier per chunk, dual PV accumulators, hw-exp2 softmax.
// grid (18, 16, 2). block 512 = 8 waves. LDS 2*(4096+4224)*2B = 32.5 KB.
__global__ __launch_bounds__(512) void attn_mfma(
    const _Float16* __restrict__ q16, const _Float16* __restrict__ k16,
    const _Float16* __restrict__ vt16, _Float16* __restrict__ a16)
{
    __shared__ _Float16 Ksm[2][8 * 512];    // [buf][kt2][slot*8 + par*4]
    __shared__ _Float16 Vsm[2][8 * 528];    // [buf][kt2][slot*8 + par*4], 528 pitch
    const int st = blockIdx.z;
    const _Float16* Qg = q16  + (size_t)st * kInpStride;
    const _Float16* Kg = k16  + (size_t)(1 - st) * kInpStride;
    const _Float16* Vg = vt16 + (size_t)(1 - st) * kInpStride;
    const int bh = blockIdx.y;
    const int bb = bh >> 3, h = bh & 7;
    const int tid  = threadIdx.x;
    const int wv   = tid >> 6;              // 0..7
    const int lane = tid & 63;
    const int r16  = lane & 15;
    const int g    = lane >> 4;

    // prefill static pad slots of BOTH buffers.
    // K: slots 32..63 zero for all kt.  V: slots with (s&15)>=8 (ones at rv==8).
    #pragma unroll
    for (int j = 0; j < 2; ++j) {
        const int s = tid;                  // 0..511
        const int kt = s >> 5, m = s & 31;
        *(half4f*)(Ksm[j] + (kt >> 1) * 512 + (32 + m) * 8 + (kt & 1) * 4) = (half4f){0, 0, 0, 0};
        const int rv = 8 + (m & 7), gv = m >> 3;
        const int vs = gv * 16 + rv;
        const half4f vvp = (rv == 8)
            ? (half4f){(_Float16)1.f, (_Float16)1.f, (_Float16)1.f, (_Float16)1.f}
            : (half4f){0, 0, 0, 0};
        *(half4f*)(Vsm[j] + (kt >> 1) * 528 + vs * 8 + (kt & 1) * 4) = vvp;
    }

    const int qg = blockIdx.x * 128 + wv * 16 + r16;
    half4f qf = (half4f){0, 0, 0, 0};
    if (g < 2) qf = *(const half4f*)(Qg + ((size_t)bh * kP + qg) * 8 + g * 4);

    // staging role: tid<256 -> K key svt; tid>=256 -> V (row vd, cols vc8..vc8+7)
    const bool isK = (tid < 256);
    const int svt = tid & 255;
    const int kkt = svt >> 4, kr = svt & 15;               // K: kt, slot
    const int vd = svt >> 5, vc8 = (svt & 31) * 8;
    const int vkt = vc8 >> 4, vgv = (vc8 & 15) >> 2;       // V: kt, gv in {0, 2}
    // frag addresses: addr(kt, s) = (kt>>1)*PAIR + s*8 + (kt&1)*4; two frags at s, s+16
    const int soff = isK ? ((kkt >> 1) * 512 + kr * 8 + (kkt & 1) * 4)
                         : ((vkt >> 1) * 528 + (vgv * 16 + vd) * 8 + (vkt & 1) * 4);
    const int soff2 = soff + 128;                          // s+16 -> +16*8 halfs
    const _Float16* ssrc = isK ? (Kg + ((size_t)bh * kP + svt) * 8)
                               : (Vg + (size_t)(bh * 8 + vd) * kP + vc8);
    const size_t sstep = isK ? 2048 : 256;   // halfs per 256-key chunk

    // preload + write chunk 0 into buffer 0
    {
        const half8 s0 = *(const half8*)ssrc;
        _Float16* base = isK ? Ksm[0] : Vsm[0];
        *(half4f*)(base + soff)  = (half4f){s0[0], s0[1], s0[2], s0[3]};
        *(half4f*)(base + soff2) = (half4f){s0[4], s0[5], s0[6], s0[7]};
    }

    f32x4 of0 = (f32x4){0.f, 0.f, 0.f, 0.f};
    f32x4 of1 = (f32x4){0.f, 0.f, 0.f, 0.f};

    for (int ch = 0; ch < 9; ++ch) {
        __syncthreads();                        // buf[ch&1] fully written
        half8 sreg;
        if (ch < 8) sreg = *(const half8*)(ssrc + (size_t)(ch + 1) * sstep);
        const _Float16* Kb = Ksm[ch & 1];
        const _Float16* Vb = Vsm[ch & 1];
        #pragma unroll
        for (int kt2 = 0; kt2 < 8; ++kt2) {
            const half8 k01 = *(const half8*)(Kb + kt2 * 512 + lane * 8);
            const half8 v01 = *(const half8*)(Vb + kt2 * 528 + lane * 8);
            // even kt
            {
                const half4f kf = {k01[0], k01[1], k01[2], k01[3]};
                f32x4 sv = __builtin_amdgcn_mfma_f32_16x16x16f16(kf, qf, (f32x4){0.f,0.f,0.f,0.f}, 0, 0, 0);
                const float e0 = __builtin_amdgcn_exp2f(sv[0]);
                const float e1 = __builtin_amdgcn_exp2f(sv[1]);
                const float e2 = __builtin_amdgcn_exp2f(sv[2]);
                const float e3 = __builtin_amdgcn_exp2f(sv[3]);
                const fp16x2 lo = __builtin_amdgcn_cvt_pkrtz(e0, e1);
                const fp16x2 hi = __builtin_amdgcn_cvt_pkrtz(e2, e3);
                const half4f pf = { (_Float16)lo[0], (_Float16)lo[1],
                                    (_Float16)hi[0], (_Float16)hi[1] };
                const half4f vf = {v01[0], v01[1], v01[2], v01[3]};
                of0 = __builtin_amdgcn_mfma_f32_16x16x16f16(vf, pf, of0, 0, 0, 0);
            }
            // odd kt
            {
                const half4f kf = {k01[4], k01[5], k01[6], k01[7]};
                f32x4 sv = __builtin_amdgcn_mfma_f32_16x16x16f16(kf, qf, (f32x4){0.f,0.f,0.f,0.f}, 0, 0, 0);
                const float e0 = __builtin_amdgcn_exp2f(sv[0]);
                const float e1 = __builtin_amdgcn_exp2f(sv[1]);
                const float e2 = __builtin_amdgcn_exp2f(sv[2]);
                const float e3 = __builtin_amdgcn_exp2f(sv[3]);
                const fp16x2 lo = __builtin_amdgcn_cvt_pkrtz(e0, e1);
                const fp16x2 hi = __builtin_amdgcn_cvt_pkrtz(e2, e3);
                const half4f pf = { (_Float16)lo[0], (_Float16)lo[1],
                                    (_Float16)hi[0], (_Float16)hi[1] };
                const half4f vf = {v01[4], v01[5], v01[6], v01[7]};
                of1 = __builtin_amdgcn_mfma_f32_16x16x16f16(vf, pf, of1, 0, 0, 0);
            }
        }
        if (ch < 8) {                           // write next chunk to other buffer
            _Float16* base = (isK ? Ksm[(ch + 1) & 1] : Vsm[(ch + 1) & 1]);
            *(half4f*)(base + soff)  = (half4f){sreg[0], sreg[1], sreg[2], sreg[3]};
            *(half4f*)(base + soff2) = (half4f){sreg[4], sreg[5], sreg[6], sreg[7]};
        }
    }
    const f32x4 of = of0 + of1;
    // rowsum lives in PV output row 8 = lane (g=2, r16), reg 0
    const float rsv = __shfl(of[0], 32 + r16, 64);
    const float inv = 1.f / rsv;
    if (g < 2) {   // lane holds d = h*8 + 4g + i at position qg
        half4f o = { (_Float16)(of[0] * inv), (_Float16)(of[1] * inv),
                     (_Float16)(of[2] * inv), (_Float16)(of[3] * inv) };
        *(half4f*)(a16 + ((size_t)(st * 2 + bb) * kP + qg) * 64 + h * 8 + g * 4) = o;
    }
}

extern "C" void kernel_launch(void* const* d_in, const int* in_sizes, int n_in,
                              void* d_out, int out_size, void* d_ws, size_t ws_size,
                              hipStream_t stream)
{
    const float* f_rgb  = (const float*)d_in[0];
    const float* f_ir   = (const float*)d_in[1];
    const float* nr_w   = (const float*)d_in[2];
    const float* nr_b   = (const float*)d_in[3];
    const float* ni_w   = (const float*)d_in[4];
    const float* ni_b   = (const float*)d_in[5];
    const float* qr_w   = (const float*)d_in[6];
    const float* qr_b   = (const float*)d_in[7];
    const float* kvi_w  = (const float*)d_in[8];
    const float* kvi_b  = (const float*)d_in[9];
    const float* qi_w   = (const float*)d_in[10];
    const float* qi_b   = (const float*)d_in[11];
    const float* kvr_w  = (const float*)d_in[12];
    const float* kvr_b  = (const float*)d_in[13];
    const float* pr_w   = (const float*)d_in[14];
    const float* pr_b   = (const float*)d_in[15];
    const float* pr_lnw = (const float*)d_in[16];
    const float* pr_lnb = (const float*)d_in[17];
    const float* pi_w   = (const float*)d_in[18];
    const float* pi_b   = (const float*)d_in[19];
    const float* pi_lnw = (const float*)d_in[20];
    const float* pi_lnb = (const float*)d_in[21];
    const float* gr_w   = (const float*)d_in[22];
    const float* gr_b   = (const float*)d_in[23];
    const float* gi_w   = (const float*)d_in[24];
    const float* gi_b   = (const float*)d_in[25];

    _Float16* hb   = (_Float16*)d_ws;
    _Float16* Xq   = hb + oXq;
    _Float16* q16  = hb + oQ16;
    _Float16* k16  = hb + oK16;
    _Float16* vt16 = hb + oV16;
    _Float16* a16  = hb + oA16;
    _Float16* Xg   = hb;            // aliases [Xq|q16|k16|vt16] (dead by then)
    _Float16* W16  = hb + oW16;
    _Float16* Aq   = W16;           // [2][192][256]
    _Float16* Ap   = W16 + 98304;   // [2][256][64]
    _Float16* Ag   = W16 + 131072;  // [2][256][512]

    float* outp = (float*)d_out;
    const dim3 blk(256);

    // 1) pre-LN (XCD-affine) + weight cast in one launch
    prep<<<dim3(1088), blk, 0, stream>>>(f_rgb, nr_w, nr_b, f_ir, ni_w, ni_b, Xq,
                                         qr_w, kvr_w, qi_w, kvi_w, pr_w, pi_w, gr_w, gi_w, W16);
    // 2) qkv GEMM (M=192, K=256)
    gemm_f16<192, 256, 0><<<dim3(432), blk, 0, stream>>>(
        Aq, Xq, qr_b, qi_b, kvr_b, kvi_b, q16, k16, vt16, nullptr, nullptr, nullptr);
    // 3) fused MFMA attention -> a16 pos-major (8 waves, dbuf, paired-kt b128 reads)
    attn_mfma<<<dim3(18, 16, 2), dim3(512), 0, stream>>>(q16, k16, vt16, a16);
    // 4) fused proj GEMM + LN + Xg build
    proj_ln<<<dim3(576), blk, 0, stream>>>(a16, Ap, pr_b, pi_b,
                                           pr_lnw, pr_lnb, pi_lnw, pi_lnb,
                                           f_rgb, f_ir, Xg);
    // 5) gate GEMM (M=256, K=512) + sigmoid + residual -> out
    gemm_f16<256, 512, 2><<<dim3(576), blk, 0, stream>>>(
        Ag, Xg, gr_b, gi_b, nullptr, nullptr, nullptr, nullptr, nullptr, f_rgb, f_ir, outp);
}